// Round 1
// baseline (831.511 us; speedup 1.0000x reference)
//
#include <hip/hip_runtime.h>

// GCN: 3 layers of (scale by norm_out) -> GEMM -> segment-sum over edges -> *norm_in + b -> relu
// N=100000 nodes, E=1600000 edges, F=H=128, C=40.
// Strategy: build CSR (dst-sorted src list) once per call, then per layer:
//   gemm_scaled: T = (norm_out .* X) @ W      (f32, W in LDS, X tile in LDS)
//   agg_kernel : out[i] = (sum_{e:dst=i} T[src_e]) * norm_in[i] + b   (wave per node, no atomics)

#define KDIM 128

// ---------------- degree ----------------
__global__ __launch_bounds__(256) void degree_kernel(const int* __restrict__ src,
                                                     const int* __restrict__ dst,
                                                     float* __restrict__ degf,
                                                     int* __restrict__ degi, int E) {
    int i = blockIdx.x * blockDim.x + threadIdx.x;
    if (i < E) {
        atomicAdd(&degf[src[i]], 1.0f);
        atomicAdd(&degi[dst[i]], 1);
    }
}

// ---------------- norms (degf -> norm_out in place) ----------------
__global__ __launch_bounds__(256) void norm_kernel(float* __restrict__ degf_normout,
                                                   const int* __restrict__ degi,
                                                   float* __restrict__ norm_in, int n) {
    int i = blockIdx.x * blockDim.x + threadIdx.x;
    if (i < n) {
        float dof = degf_normout[i];
        degf_normout[i] = (dof > 0.0f) ? rsqrtf(dof) : 0.0f;
        int di = degi[i];
        norm_in[i] = (di > 0) ? rsqrtf((float)di) : 0.0f;
    }
}

// ---------------- scan (exclusive prefix sum of deg_in -> row_off) ----------------
__global__ __launch_bounds__(256) void scan1_kernel(const int* __restrict__ degi,
                                                    int* __restrict__ row_off,
                                                    int* __restrict__ bsum, int n) {
    __shared__ int s[256];
    int t = threadIdx.x;
    int i = blockIdx.x * 256 + t;
    int v = (i < n) ? degi[i] : 0;
    s[t] = v;
    __syncthreads();
    for (int off = 1; off < 256; off <<= 1) {
        int x = (t >= off) ? s[t - off] : 0;
        __syncthreads();
        s[t] += x;
        __syncthreads();
    }
    if (i < n) row_off[i + 1] = s[t];   // within-block inclusive scan
    if (t == 255) bsum[blockIdx.x] = s[t];
}

__global__ __launch_bounds__(512) void scan2_kernel(const int* __restrict__ bsum,
                                                    int* __restrict__ boff, int nb) {
    __shared__ int s[512];
    int t = threadIdx.x;
    int v = (t < nb) ? bsum[t] : 0;
    s[t] = v;
    __syncthreads();
    for (int off = 1; off < 512; off <<= 1) {
        int x = (t >= off) ? s[t - off] : 0;
        __syncthreads();
        s[t] += x;
        __syncthreads();
    }
    boff[t] = s[t] - v;                 // exclusive block offsets
}

__global__ __launch_bounds__(256) void scan3_kernel(int* __restrict__ row_off,
                                                    const int* __restrict__ boff, int n) {
    int i = blockIdx.x * blockDim.x + threadIdx.x;
    if (i < n) row_off[i + 1] += boff[i >> 8];
    if (i == 0) row_off[0] = 0;
}

// ---------------- CSR fill (counting sort by dst) ----------------
__global__ __launch_bounds__(256) void fill_kernel(const int* __restrict__ src,
                                                   const int* __restrict__ dst,
                                                   const int* __restrict__ row_off,
                                                   int* __restrict__ cursor,
                                                   int* __restrict__ ssrc, int E) {
    int e = blockIdx.x * blockDim.x + threadIdx.x;
    if (e < E) {
        int d = dst[e];
        int r = atomicAdd(&cursor[d], 1);
        ssrc[row_off[d] + r] = src[e];
    }
}

// ---------------- GEMM: T = (norm .* X) @ W,  X: nrows x 128, W: 128 x M ----------------
template <int M, int RPB, int CPT>
__global__ __launch_bounds__(256) void gemm_scaled(const float* __restrict__ X,
                                                   const float* __restrict__ nrm,
                                                   const float* __restrict__ W,
                                                   float* __restrict__ T, int nrows) {
    constexpr int CG = M / CPT;   // col groups
    constexpr int RG = RPB / 2;   // row groups (2 rows per thread)
    static_assert(CG * RG == 256, "thread mapping");
    __shared__ float xs[KDIM][RPB + 1];   // transposed, padded
    __shared__ float ws[64][M];           // K-chunk of W

    const int t = threadIdx.x;
    const int rowbase = blockIdx.x * RPB;

    // stage X tile, scaled by norm_out[row]
    {
        constexpr int NV = RPB * (KDIM / 4) / 256;  // float4s per thread
        const float4* X4 = reinterpret_cast<const float4*>(X);
#pragma unroll
        for (int i = 0; i < NV; ++i) {
            int idx = t + i * 256;
            int rl = idx >> 5;        // 32 float4 per row
            int kq = idx & 31;
            int row = rowbase + rl;
            float4 v = make_float4(0.f, 0.f, 0.f, 0.f);
            float s = 0.f;
            if (row < nrows) { v = X4[row * 32 + kq]; s = nrm[row]; }
            xs[4 * kq + 0][rl] = v.x * s;
            xs[4 * kq + 1][rl] = v.y * s;
            xs[4 * kq + 2][rl] = v.z * s;
            xs[4 * kq + 3][rl] = v.w * s;
        }
    }

    const int rg = t / CG, cg = t % CG;
    const int r0 = 2 * rg, cb = cg * CPT;
    float acc0[CPT] = {0.f}, acc1[CPT] = {0.f};

    for (int kc = 0; kc < 2; ++kc) {
        __syncthreads();  // also covers xs staging on first pass
        {
            constexpr int TOT4 = 64 * M / 4;
            const float4* W4 = reinterpret_cast<const float4*>(W);
            for (int i = t; i < TOT4; i += 256) {
                int kk = i / (M / 4), m4 = i % (M / 4);
                float4 v = W4[(kc * 64 + kk) * (M / 4) + m4];
                ws[kk][4 * m4 + 0] = v.x;
                ws[kk][4 * m4 + 1] = v.y;
                ws[kk][4 * m4 + 2] = v.z;
                ws[kk][4 * m4 + 3] = v.w;
            }
        }
        __syncthreads();
#pragma unroll 8
        for (int k = 0; k < 64; ++k) {
            float xv0 = xs[kc * 64 + k][r0];
            float xv1 = xs[kc * 64 + k][r0 + 1];
#pragma unroll
            for (int j = 0; j < CPT; ++j) {
                float wv = ws[k][cb + j];
                acc0[j] = fmaf(xv0, wv, acc0[j]);
                acc1[j] = fmaf(xv1, wv, acc1[j]);
            }
        }
    }

    int row0 = rowbase + r0;
    if (row0 < nrows) {
#pragma unroll
        for (int j = 0; j < CPT; ++j) T[(size_t)row0 * M + cb + j] = acc0[j];
    }
    if (row0 + 1 < nrows) {
#pragma unroll
        for (int j = 0; j < CPT; ++j) T[(size_t)(row0 + 1) * M + cb + j] = acc1[j];
    }
}

// ---------------- aggregation: wave per node, register accumulate ----------------
template <int M, bool RELU>
__global__ __launch_bounds__(256) void agg_kernel(const float* __restrict__ T,
                                                  const int* __restrict__ row_off,
                                                  const int* __restrict__ ssrc,
                                                  const float* __restrict__ norm_in,
                                                  const float* __restrict__ bias,
                                                  float* __restrict__ out, int n) {
    const int wid = (int)((blockIdx.x * blockDim.x + threadIdx.x) >> 6);
    const int lane = threadIdx.x & 63;
    if (wid >= n) return;
    constexpr int L = M / 2;  // active lanes (float2 each)
    const float2* T2 = reinterpret_cast<const float2*>(T);
    const int e0 = row_off[wid], e1 = row_off[wid + 1];
    if (lane < L) {
        float ax = 0.f, ay = 0.f;
        int e = e0;
        for (; e + 4 <= e1; e += 4) {
            int s0 = ssrc[e], s1 = ssrc[e + 1], s2 = ssrc[e + 2], s3 = ssrc[e + 3];
            float2 v0 = T2[s0 * L + lane];
            float2 v1 = T2[s1 * L + lane];
            float2 v2 = T2[s2 * L + lane];
            float2 v3 = T2[s3 * L + lane];
            ax += (v0.x + v1.x) + (v2.x + v3.x);
            ay += (v0.y + v1.y) + (v2.y + v3.y);
        }
        for (; e < e1; ++e) {
            int s = ssrc[e];
            float2 v = T2[s * L + lane];
            ax += v.x;
            ay += v.y;
        }
        float ni = norm_in[wid];
        float2 b = reinterpret_cast<const float2*>(bias)[lane];
        float ox = ax * ni + b.x;
        float oy = ay * ni + b.y;
        if (RELU) { ox = fmaxf(ox, 0.f); oy = fmaxf(oy, 0.f); }
        reinterpret_cast<float2*>(out)[(size_t)wid * L + lane] = make_float2(ox, oy);
    }
}

// ---------------- launch ----------------
extern "C" void kernel_launch(void* const* d_in, const int* in_sizes, int n_in,
                              void* d_out, int out_size, void* d_ws, size_t ws_size,
                              hipStream_t stream) {
    const float* feat = (const float*)d_in[0];
    const int* src = (const int*)d_in[1];
    const int* dst = (const int*)d_in[2];
    const float* W0 = (const float*)d_in[3];
    const float* b0 = (const float*)d_in[4];
    const float* W1 = (const float*)d_in[5];
    const float* b1 = (const float*)d_in[6];
    const float* W2 = (const float*)d_in[7];
    const float* b2 = (const float*)d_in[8];
    float* outp = (float*)d_out;

    const int N = in_sizes[0] / KDIM;   // 100000
    const int E = in_sizes[1];          // 1600000
    const int C = in_sizes[8];          // 40

    // workspace layout (256B aligned chunks)
    auto align = [](size_t x) { return (x + 255) & ~(size_t)255; };
    char* p = (char*)d_ws;
    float* degf_normout = (float*)p;            p += align((size_t)N * 4);
    int* degi           = (int*)p;              p += align((size_t)N * 4);
    int* cursor         = (int*)p;              p += align((size_t)N * 4);
    float* norm_in      = (float*)p;            p += align((size_t)N * 4);
    int* row_off        = (int*)p;              p += align((size_t)(N + 1) * 4);
    int* bsum           = (int*)p;              p += align(512 * 4);
    int* boff           = (int*)p;              p += align(512 * 4);
    int* ssrc           = (int*)p;              p += align((size_t)E * 4);
    float* T            = (float*)p;            p += align((size_t)N * KDIM * 4);
    float* H            = (float*)p;            p += align((size_t)N * KDIM * 4);
    (void)ws_size; (void)n_in; (void)out_size;

    const int nbN = (N + 255) / 256;    // 391
    const int nbE = (E + 255) / 256;    // 6250

    // zero the accumulators (ws is poisoned before every call)
    hipMemsetAsync(degf_normout, 0, (size_t)N * 4, stream);
    hipMemsetAsync(degi, 0, (size_t)N * 4, stream);
    hipMemsetAsync(cursor, 0, (size_t)N * 4, stream);

    // degrees + norms
    degree_kernel<<<nbE, 256, 0, stream>>>(src, dst, degf_normout, degi, E);
    norm_kernel<<<nbN, 256, 0, stream>>>(degf_normout, degi, norm_in, N);

    // exclusive scan of deg_in -> row_off
    scan1_kernel<<<nbN, 256, 0, stream>>>(degi, row_off, bsum, N);
    scan2_kernel<<<1, 512, 0, stream>>>(bsum, boff, nbN);
    scan3_kernel<<<nbN, 256, 0, stream>>>(row_off, boff, N);

    // CSR fill
    fill_kernel<<<nbE, 256, 0, stream>>>(src, dst, row_off, cursor, ssrc, E);

    const int aggBlocks = (int)(((size_t)N * 64 + 255) / 256);  // wave per node

    // layer 1: feat -> H
    gemm_scaled<128, 32, 8><<<(N + 31) / 32, 256, 0, stream>>>(feat, degf_normout, W0, T, N);
    agg_kernel<128, true><<<aggBlocks, 256, 0, stream>>>(T, row_off, ssrc, norm_in, b0, H, N);

    // layer 2: H -> H (via T)
    gemm_scaled<128, 32, 8><<<(N + 31) / 32, 256, 0, stream>>>(H, degf_normout, W1, T, N);
    agg_kernel<128, true><<<aggBlocks, 256, 0, stream>>>(T, row_off, ssrc, norm_in, b1, H, N);

    // layer 3: H -> d_out (C=40)
    gemm_scaled<40, 64, 5><<<(N + 63) / 64, 256, 0, stream>>>(H, degf_normout, W2, T, N);
    agg_kernel<40, false><<<aggBlocks, 256, 0, stream>>>(T, row_off, ssrc, norm_in, b2, outp, N);
    (void)C;
}

// Round 5
// 779.283 us; speedup vs baseline: 1.0670x; 1.0670x over previous
//
#include <hip/hip_runtime.h>

// GCN: 3 x [ (norm_out .* X) @ W  ->  segment-sum over edges  ->  *norm_in + b -> relu ]
// N=100000, E=1600000, F=H=128, C=40.
// Round 5: round-1's PROVEN agg kernel (float2, serial edges) + single-pass build
//          (slots aliased into dead T) + scan + compact -> round-1's exact CSR.
//          Deltas vs round-1 are build-side only => clean bisect of rounds 2-4 failure.
// ws: 110.41MB < 110.80MB (round-1 proven).

#define KDIM 128
#define CAP 48        // P(Poisson(16) > 48) ~ 1e-11; overflow path keeps it exact anyway
#define OVFMAX 1024

// ---------------- build: out-deg histogram + in-deg rank + slot store + overflow ----------------
__global__ __launch_bounds__(256) void build_kernel(const int* __restrict__ src,
                                                    const int* __restrict__ dst,
                                                    int* __restrict__ degO,
                                                    int* __restrict__ cursor,
                                                    int* __restrict__ slots,
                                                    int2* __restrict__ ovf,
                                                    int* __restrict__ ovfcnt, int E) {
    int i = blockIdx.x * blockDim.x + threadIdx.x;
    if (i < E) {
        int s = src[i], d = dst[i];
        atomicAdd(&degO[s], 1);
        int r = atomicAdd(&cursor[d], 1);
        if (r < CAP) {
            slots[d * CAP + r] = s;
        } else {
            int o = atomicAdd(ovfcnt, 1);
            if (o < OVFMAX) ovf[o] = make_int2((d << 8) | (r - CAP), s);
        }
    }
}

// ---------------- norm_in from in-degree ----------------
__global__ __launch_bounds__(256) void norm_kernel(const int* __restrict__ cursor,
                                                   float* __restrict__ norm_in, int n) {
    int i = blockIdx.x * blockDim.x + threadIdx.x;
    if (i < n) {
        int di = cursor[i];
        norm_in[i] = (di > 0) ? rsqrtf((float)di) : 0.0f;
    }
}

// ---------------- scans: exclusive prefix sum of cursor -> row_off ----------------
__global__ __launch_bounds__(256) void scan1_kernel(const int* __restrict__ cnt,
                                                    int* __restrict__ row_off,
                                                    int* __restrict__ bsum, int n) {
    __shared__ int sm[256];
    int t = threadIdx.x;
    int i = blockIdx.x * 256 + t;
    int v = (i < n) ? cnt[i] : 0;
    sm[t] = v;
    __syncthreads();
    for (int off = 1; off < 256; off <<= 1) {
        int x = (t >= off) ? sm[t - off] : 0;
        __syncthreads();
        sm[t] += x;
        __syncthreads();
    }
    if (i < n) row_off[i + 1] = sm[t];
    if (t == 255) bsum[blockIdx.x] = sm[t];
}

__global__ __launch_bounds__(512) void scan2_kernel(const int* __restrict__ bsum,
                                                    int* __restrict__ boff, int nb) {
    __shared__ int sm[512];
    int t = threadIdx.x;
    int v = (t < nb) ? bsum[t] : 0;
    sm[t] = v;
    __syncthreads();
    for (int off = 1; off < 512; off <<= 1) {
        int x = (t >= off) ? sm[t - off] : 0;
        __syncthreads();
        sm[t] += x;
        __syncthreads();
    }
    boff[t] = sm[t] - v;
}

__global__ __launch_bounds__(256) void scan3_kernel(int* __restrict__ row_off,
                                                    const int* __restrict__ boff, int n) {
    int i = blockIdx.x * blockDim.x + threadIdx.x;
    if (i < n) row_off[i + 1] += boff[i >> 8];
    if (i == 0) row_off[0] = 0;
}

// ---------------- compact: slots (strided, in T) -> ssrc (compact CSR) ----------------
__global__ __launch_bounds__(256) void compact_kernel(const int* __restrict__ slots,
                                                      const int* __restrict__ cursor,
                                                      const int* __restrict__ row_off,
                                                      int* __restrict__ ssrc, int n) {
    int t = blockIdx.x * blockDim.x + threadIdx.x;
    int d = t / CAP, r = t % CAP;
    if (d < n) {
        int c = cursor[d];
        if (c > CAP) c = CAP;
        if (r < c) ssrc[row_off[d] + r] = slots[d * CAP + r];
    }
}

__global__ __launch_bounds__(256) void ovf_kernel(const int2* __restrict__ ovf,
                                                  const int* __restrict__ ovfcnt,
                                                  const int* __restrict__ row_off,
                                                  int* __restrict__ ssrc) {
    int t = blockIdx.x * blockDim.x + threadIdx.x;
    int no = *ovfcnt;
    if (no > OVFMAX) no = OVFMAX;
    if (t < no) {
        int2 p = ovf[t];
        int d = p.x >> 8, rr = p.x & 255;
        ssrc[row_off[d] + CAP + rr] = p.y;
    }
}

// ---------------- GEMM: T = (norm_out .* X) @ W,  X: nrows x 128, W: 128 x M ----------------
// Identical to round-1's passing kernel except norm_out = rsqrt(degO) computed inline.
template <int M, int RPB, int CPT>
__global__ __launch_bounds__(256) void gemm_scaled(const float* __restrict__ X,
                                                   const int* __restrict__ degO,
                                                   const float* __restrict__ W,
                                                   float* __restrict__ T, int nrows) {
    constexpr int CG = M / CPT;
    static_assert(CG * (RPB / 2) == 256, "thread mapping");
    __shared__ float xs[KDIM][RPB + 1];
    __shared__ float ws[64][M];

    const int t = threadIdx.x;
    const int rowbase = blockIdx.x * RPB;

    {
        constexpr int NV = RPB * (KDIM / 4) / 256;
        const float4* X4 = reinterpret_cast<const float4*>(X);
#pragma unroll
        for (int i = 0; i < NV; ++i) {
            int idx = t + i * 256;
            int rl = idx >> 5;
            int kq = idx & 31;
            int row = rowbase + rl;
            float4 v = make_float4(0.f, 0.f, 0.f, 0.f);
            float s = 0.f;
            if (row < nrows) {
                v = X4[(size_t)row * 32 + kq];
                int dv = degO[row];
                s = (dv > 0) ? rsqrtf((float)dv) : 0.0f;
            }
            xs[4 * kq + 0][rl] = v.x * s;
            xs[4 * kq + 1][rl] = v.y * s;
            xs[4 * kq + 2][rl] = v.z * s;
            xs[4 * kq + 3][rl] = v.w * s;
        }
    }

    const int rg = t / CG, cg = t % CG;
    const int r0 = 2 * rg, cb = cg * CPT;
    float acc0[CPT] = {0.f}, acc1[CPT] = {0.f};

    for (int kc = 0; kc < 2; ++kc) {
        __syncthreads();
        {
            constexpr int TOT4 = 64 * M / 4;
            const float4* W4 = reinterpret_cast<const float4*>(W);
            for (int i = t; i < TOT4; i += 256) {
                int kk = i / (M / 4), m4 = i % (M / 4);
                float4 v = W4[(size_t)(kc * 64 + kk) * (M / 4) + m4];
                ws[kk][4 * m4 + 0] = v.x;
                ws[kk][4 * m4 + 1] = v.y;
                ws[kk][4 * m4 + 2] = v.z;
                ws[kk][4 * m4 + 3] = v.w;
            }
        }
        __syncthreads();
#pragma unroll 8
        for (int k = 0; k < 64; ++k) {
            float xv0 = xs[kc * 64 + k][r0];
            float xv1 = xs[kc * 64 + k][r0 + 1];
#pragma unroll
            for (int j = 0; j < CPT; ++j) {
                float wv = ws[k][cb + j];
                acc0[j] = fmaf(xv0, wv, acc0[j]);
                acc1[j] = fmaf(xv1, wv, acc1[j]);
            }
        }
    }

    int row0 = rowbase + r0;
    if (row0 < nrows) {
#pragma unroll
        for (int j = 0; j < CPT; ++j) T[(size_t)row0 * M + cb + j] = acc0[j];
    }
    if (row0 + 1 < nrows) {
#pragma unroll
        for (int j = 0; j < CPT; ++j) T[(size_t)(row0 + 1) * M + cb + j] = acc1[j];
    }
}

// ---------------- aggregation: ROUND-1 PROVEN KERNEL, verbatim ----------------
template <int M, bool RELU>
__global__ __launch_bounds__(256) void agg_kernel(const float* __restrict__ T,
                                                  const int* __restrict__ row_off,
                                                  const int* __restrict__ ssrc,
                                                  const float* __restrict__ norm_in,
                                                  const float* __restrict__ bias,
                                                  float* __restrict__ out, int n) {
    const int wid = (int)((blockIdx.x * blockDim.x + threadIdx.x) >> 6);
    const int lane = threadIdx.x & 63;
    if (wid >= n) return;
    constexpr int L = M / 2;  // active lanes (float2 each)
    const float2* T2 = reinterpret_cast<const float2*>(T);
    const int e0 = row_off[wid], e1 = row_off[wid + 1];
    if (lane < L) {
        float ax = 0.f, ay = 0.f;
        int e = e0;
        for (; e + 4 <= e1; e += 4) {
            int s0 = ssrc[e], s1 = ssrc[e + 1], s2 = ssrc[e + 2], s3 = ssrc[e + 3];
            float2 v0 = T2[s0 * L + lane];
            float2 v1 = T2[s1 * L + lane];
            float2 v2 = T2[s2 * L + lane];
            float2 v3 = T2[s3 * L + lane];
            ax += (v0.x + v1.x) + (v2.x + v3.x);
            ay += (v0.y + v1.y) + (v2.y + v3.y);
        }
        for (; e < e1; ++e) {
            int s = ssrc[e];
            float2 v = T2[s * L + lane];
            ax += v.x;
            ay += v.y;
        }
        float ni = norm_in[wid];
        float2 b = reinterpret_cast<const float2*>(bias)[lane];
        float ox = ax * ni + b.x;
        float oy = ay * ni + b.y;
        if (RELU) { ox = fmaxf(ox, 0.f); oy = fmaxf(oy, 0.f); }
        reinterpret_cast<float2*>(out)[(size_t)wid * L + lane] = make_float2(ox, oy);
    }
}

// ---------------- launch ----------------
extern "C" void kernel_launch(void* const* d_in, const int* in_sizes, int n_in,
                              void* d_out, int out_size, void* d_ws, size_t ws_size,
                              hipStream_t stream) {
    const float* feat = (const float*)d_in[0];
    const int* src = (const int*)d_in[1];
    const int* dst = (const int*)d_in[2];
    const float* W0 = (const float*)d_in[3];
    const float* b0 = (const float*)d_in[4];
    const float* W1 = (const float*)d_in[5];
    const float* b1 = (const float*)d_in[6];
    const float* W2 = (const float*)d_in[7];
    const float* b2 = (const float*)d_in[8];
    float* outp = (float*)d_out;

    const int N = in_sizes[0] / KDIM;   // 100000
    const int E = in_sizes[1];          // 1600000

    auto align = [](size_t x) { return (x + 255) & ~(size_t)255; };
    char* p = (char*)d_ws;
    int* degO      = (int*)p;    p += align((size_t)N * 4);
    int* cursor    = (int*)p;    p += align((size_t)N * 4);
    int* ovfcnt    = (int*)p;    p += align(4);
    int2* ovf      = (int2*)p;   p += align((size_t)OVFMAX * 8);
    float* norm_in = (float*)p;  p += align((size_t)N * 4);
    int* row_off   = (int*)p;    p += align((size_t)(N + 1) * 4);
    int* bsum      = (int*)p;    p += align(512 * 4);
    int* boff      = (int*)p;    p += align(512 * 4);
    int* ssrc      = (int*)p;    p += align((size_t)E * 4);
    float* T       = (float*)p;  p += align((size_t)N * KDIM * 4);
    float* H       = (float*)p;  p += align((size_t)N * KDIM * 4);
    int* slots     = (int*)T;    // alias: T is dead until first GEMM (compact runs first)
    (void)n_in; (void)out_size; (void)ws_size;
    // total = 110.41MB < 110.80MB proven in round 1

    const int nbN = (N + 255) / 256;
    const int nbE = (E + 255) / 256;
    const int aggBlocks = (int)(((size_t)N * 64 + 255) / 256);  // wave per node

    // degO, cursor, ovfcnt contiguous -> one memset
    hipMemsetAsync(degO, 0, 2 * align((size_t)N * 4) + 256, stream);

    // build graph structure (slots live in T's memory), then compact to round-1 CSR
    build_kernel<<<nbE, 256, 0, stream>>>(src, dst, degO, cursor, slots, ovf, ovfcnt, E);
    norm_kernel<<<nbN, 256, 0, stream>>>(cursor, norm_in, N);
    scan1_kernel<<<nbN, 256, 0, stream>>>(cursor, row_off, bsum, N);
    scan2_kernel<<<1, 512, 0, stream>>>(bsum, boff, nbN);
    scan3_kernel<<<nbN, 256, 0, stream>>>(row_off, boff, N);
    compact_kernel<<<(N * CAP + 255) / 256, 256, 0, stream>>>(slots, cursor, row_off, ssrc, N);
    ovf_kernel<<<OVFMAX / 256, 256, 0, stream>>>(ovf, ovfcnt, row_off, ssrc);

    // layer 1: feat -> T -> H   (first GEMM overwrites slot area; compact already done)
    gemm_scaled<128, 32, 8><<<(N + 31) / 32, 256, 0, stream>>>(feat, degO, W0, T, N);
    agg_kernel<128, true><<<aggBlocks, 256, 0, stream>>>(T, row_off, ssrc, norm_in, b0, H, N);

    // layer 2: H -> T -> H
    gemm_scaled<128, 32, 8><<<(N + 31) / 32, 256, 0, stream>>>(H, degO, W1, T, N);
    agg_kernel<128, true><<<aggBlocks, 256, 0, stream>>>(T, row_off, ssrc, norm_in, b1, H, N);

    // layer 3: H -> T -> out (C=40)
    gemm_scaled<40, 64, 5><<<(N + 63) / 64, 256, 0, stream>>>(H, degO, W2, T, N);
    agg_kernel<40, false><<<aggBlocks, 256, 0, stream>>>(T, row_off, ssrc, norm_in, b2, outp, N);
}

// Round 6
// 668.143 us; speedup vs baseline: 1.2445x; 1.1663x over previous
//
#include <hip/hip_runtime.h>

// GCN: 3 x [ (norm_out .* X) @ W  ->  segment-sum over edges  ->  *norm_in + b -> relu ]
// N=100000, E=1600000, F=H=128, C=40.
// Round 6: binned counting-sort CSR build (replaces atomic slot-scatter build):
//   B0  : bucket histograms of dst>>8 and src>>8 (LDS-privatized, 391 buckets)
//   B0b : exact bucket offsets (one-block scan)
//   B1  : bin edges into exact bucket regions (packed src|(dst&255)<<17), block-contiguous
//   B2  : per-bucket: per-node histogram -> row_off/norm_in/degO (NO atomics), scatter -> ssrc
// GEMM + agg are round-5 proven code, verbatim. Bins alias into dead T. ws ~110.0MB (<110.8 proven).
// Assumes N <= 131072 (17-bit src packing) and N <= 131072 -> nb <= 512 LDS counters.

#define KDIM 128
#define EPB 4096   // edges per block in B0/B1 (16 per thread)

// ---------------- B0: bucket counts ----------------
__global__ __launch_bounds__(256) void b0_count(const int* __restrict__ src,
                                                const int* __restrict__ dst,
                                                int* __restrict__ gcntA,
                                                int* __restrict__ gcntB, int E, int nb) {
    __shared__ int hA[512], hB[512];
    const int t = threadIdx.x;
    for (int b = t; b < nb; b += 256) { hA[b] = 0; hB[b] = 0; }
    __syncthreads();
    const int base = blockIdx.x * EPB;
#pragma unroll
    for (int i = 0; i < 16; ++i) {
        int e = base + i * 256 + t;
        if (e < E) {
            atomicAdd(&hA[dst[e] >> 8], 1);
            atomicAdd(&hB[src[e] >> 8], 1);
        }
    }
    __syncthreads();
    for (int b = t; b < nb; b += 256) {
        if (hA[b]) atomicAdd(&gcntA[b], hA[b]);
        if (hB[b]) atomicAdd(&gcntB[b], hB[b]);
    }
}

// ---------------- B0b: exclusive scan of bucket counts -> offsets + cursors ----------------
__global__ __launch_bounds__(512) void b0b_offsets(const int* __restrict__ gcntA,
                                                   const int* __restrict__ gcntB,
                                                   int* __restrict__ offA,
                                                   int* __restrict__ offB,
                                                   int* __restrict__ gcurA,
                                                   int* __restrict__ gcurB,
                                                   int* __restrict__ row_off,
                                                   int nb, int N, int E) {
    __shared__ int sm[512];
    const int t = threadIdx.x;
    // scan A
    int v = (t < nb) ? gcntA[t] : 0;
    sm[t] = v;
    __syncthreads();
    for (int o = 1; o < 512; o <<= 1) {
        int x = (t >= o) ? sm[t - o] : 0;
        __syncthreads();
        sm[t] += x;
        __syncthreads();
    }
    if (t < nb) { offA[t + 1] = sm[t]; gcurA[t] = sm[t] - v; }
    if (t == 0) { offA[0] = 0; row_off[N] = E; }
    __syncthreads();
    // scan B
    int vb = (t < nb) ? gcntB[t] : 0;
    sm[t] = vb;
    __syncthreads();
    for (int o = 1; o < 512; o <<= 1) {
        int x = (t >= o) ? sm[t - o] : 0;
        __syncthreads();
        sm[t] += x;
        __syncthreads();
    }
    if (t < nb) { offB[t + 1] = sm[t]; gcurB[t] = sm[t] - vb; }
    if (t == 0) offB[0] = 0;
}

// ---------------- B1: bin edges into exact bucket regions ----------------
__global__ __launch_bounds__(256) void b1_bin(const int* __restrict__ src,
                                              const int* __restrict__ dst,
                                              int* __restrict__ gcurA,
                                              int* __restrict__ gcurB,
                                              int* __restrict__ binA,
                                              int* __restrict__ binB, int E, int nb) {
    __shared__ int hA[512], hB[512];
    const int t = threadIdx.x;
    for (int b = t; b < nb; b += 256) { hA[b] = 0; hB[b] = 0; }
    __syncthreads();
    const int base = blockIdx.x * EPB;
    int se[16], de[16];
#pragma unroll
    for (int i = 0; i < 16; ++i) {
        int e = base + i * 256 + t;
        se[i] = -1; de[i] = 0;
        if (e < E) {
            se[i] = src[e]; de[i] = dst[e];
            atomicAdd(&hA[de[i] >> 8], 1);
            atomicAdd(&hB[se[i] >> 8], 1);
        }
    }
    __syncthreads();
    // reserve block-contiguous chunks per bucket; hX[b] becomes absolute write cursor
    for (int b = t; b < nb; b += 256) {
        int c = hA[b];
        hA[b] = c ? atomicAdd(&gcurA[b], c) : 0;
        c = hB[b];
        hB[b] = c ? atomicAdd(&gcurB[b], c) : 0;
    }
    __syncthreads();
#pragma unroll
    for (int i = 0; i < 16; ++i) {
        if (se[i] >= 0) {
            int pA = atomicAdd(&hA[de[i] >> 8], 1);
            binA[pA] = se[i] | ((de[i] & 255) << 17);     // src (17b) | dst-low (8b)
            int pB = atomicAdd(&hB[se[i] >> 8], 1);
            binB[pB] = se[i] & 255;                       // src-low for out-degree count
        }
    }
}

// ---------------- B2: per-bucket finalize: row_off/norm_in/degO + scatter to ssrc ----------------
__global__ __launch_bounds__(256) void b2_final(const int* __restrict__ binA,
                                                const int* __restrict__ binB,
                                                const int* __restrict__ offA,
                                                const int* __restrict__ offB,
                                                int* __restrict__ ssrc,
                                                int* __restrict__ row_off,
                                                float* __restrict__ norm_in,
                                                int* __restrict__ degO, int N) {
    __shared__ int h[256], cur[256];
    const int b = blockIdx.x, t = threadIdx.x;
    const int nA0 = offA[b], cntA = offA[b + 1] - nA0;
    const int nodes = min(256, N - b * 256);

    // pass 1: per-node in-degree histogram
    h[t] = 0;
    __syncthreads();
    for (int k = t; k < cntA; k += 256) atomicAdd(&h[binA[nA0 + k] >> 17], 1);
    __syncthreads();

    // inclusive scan (Hillis-Steele) -> exclusive in-bucket offsets
    int v = h[t];
    cur[t] = v;
    __syncthreads();
    for (int o = 1; o < 256; o <<= 1) {
        int x = (t >= o) ? cur[t - o] : 0;
        __syncthreads();
        cur[t] += x;
        __syncthreads();
    }
    const int rbase = nA0 + (cur[t] - v);   // absolute ssrc base for node b*256+t
    if (t < nodes) {
        row_off[b * 256 + t] = rbase;
        norm_in[b * 256 + t] = (v > 0) ? rsqrtf((float)v) : 0.0f;
    }
    __syncthreads();
    cur[t] = rbase;                          // running write cursor
    __syncthreads();

    // pass 2: scatter into final CSR order
    for (int k = t; k < cntA; k += 256) {
        int val = binA[nA0 + k];
        int pos = atomicAdd(&cur[val >> 17], 1);
        ssrc[pos] = val & 0x1FFFF;
    }

    // part B: out-degree histogram
    __syncthreads();
    h[t] = 0;
    __syncthreads();
    const int nB0 = offB[b], cntB = offB[b + 1] - nB0;
    for (int k = t; k < cntB; k += 256) atomicAdd(&h[binB[nB0 + k]], 1);
    __syncthreads();
    if (t < nodes) degO[b * 256 + t] = h[t];
}

// ---------------- GEMM: T = (norm_out .* X) @ W  (round-5 proven, verbatim) ----------------
template <int M, int RPB, int CPT>
__global__ __launch_bounds__(256) void gemm_scaled(const float* __restrict__ X,
                                                   const int* __restrict__ degO,
                                                   const float* __restrict__ W,
                                                   float* __restrict__ T, int nrows) {
    constexpr int CG = M / CPT;
    static_assert(CG * (RPB / 2) == 256, "thread mapping");
    __shared__ float xs[KDIM][RPB + 1];
    __shared__ float ws[64][M];

    const int t = threadIdx.x;
    const int rowbase = blockIdx.x * RPB;

    {
        constexpr int NV = RPB * (KDIM / 4) / 256;
        const float4* X4 = reinterpret_cast<const float4*>(X);
#pragma unroll
        for (int i = 0; i < NV; ++i) {
            int idx = t + i * 256;
            int rl = idx >> 5;
            int kq = idx & 31;
            int row = rowbase + rl;
            float4 v = make_float4(0.f, 0.f, 0.f, 0.f);
            float s = 0.f;
            if (row < nrows) {
                v = X4[(size_t)row * 32 + kq];
                int dv = degO[row];
                s = (dv > 0) ? rsqrtf((float)dv) : 0.0f;
            }
            xs[4 * kq + 0][rl] = v.x * s;
            xs[4 * kq + 1][rl] = v.y * s;
            xs[4 * kq + 2][rl] = v.z * s;
            xs[4 * kq + 3][rl] = v.w * s;
        }
    }

    const int rg = t / CG, cg = t % CG;
    const int r0 = 2 * rg, cb = cg * CPT;
    float acc0[CPT] = {0.f}, acc1[CPT] = {0.f};

    for (int kc = 0; kc < 2; ++kc) {
        __syncthreads();
        {
            constexpr int TOT4 = 64 * M / 4;
            const float4* W4 = reinterpret_cast<const float4*>(W);
            for (int i = t; i < TOT4; i += 256) {
                int kk = i / (M / 4), m4 = i % (M / 4);
                float4 v = W4[(size_t)(kc * 64 + kk) * (M / 4) + m4];
                ws[kk][4 * m4 + 0] = v.x;
                ws[kk][4 * m4 + 1] = v.y;
                ws[kk][4 * m4 + 2] = v.z;
                ws[kk][4 * m4 + 3] = v.w;
            }
        }
        __syncthreads();
#pragma unroll 8
        for (int k = 0; k < 64; ++k) {
            float xv0 = xs[kc * 64 + k][r0];
            float xv1 = xs[kc * 64 + k][r0 + 1];
#pragma unroll
            for (int j = 0; j < CPT; ++j) {
                float wv = ws[k][cb + j];
                acc0[j] = fmaf(xv0, wv, acc0[j]);
                acc1[j] = fmaf(xv1, wv, acc1[j]);
            }
        }
    }

    int row0 = rowbase + r0;
    if (row0 < nrows) {
#pragma unroll
        for (int j = 0; j < CPT; ++j) T[(size_t)row0 * M + cb + j] = acc0[j];
    }
    if (row0 + 1 < nrows) {
#pragma unroll
        for (int j = 0; j < CPT; ++j) T[(size_t)(row0 + 1) * M + cb + j] = acc1[j];
    }
}

// ---------------- aggregation (round-1/5 proven, verbatim) ----------------
template <int M, bool RELU>
__global__ __launch_bounds__(256) void agg_kernel(const float* __restrict__ T,
                                                  const int* __restrict__ row_off,
                                                  const int* __restrict__ ssrc,
                                                  const float* __restrict__ norm_in,
                                                  const float* __restrict__ bias,
                                                  float* __restrict__ out, int n) {
    const int wid = (int)((blockIdx.x * blockDim.x + threadIdx.x) >> 6);
    const int lane = threadIdx.x & 63;
    if (wid >= n) return;
    constexpr int L = M / 2;  // active lanes (float2 each)
    const float2* T2 = reinterpret_cast<const float2*>(T);
    const int e0 = row_off[wid], e1 = row_off[wid + 1];
    if (lane < L) {
        float ax = 0.f, ay = 0.f;
        int e = e0;
        for (; e + 4 <= e1; e += 4) {
            int s0 = ssrc[e], s1 = ssrc[e + 1], s2 = ssrc[e + 2], s3 = ssrc[e + 3];
            float2 v0 = T2[s0 * L + lane];
            float2 v1 = T2[s1 * L + lane];
            float2 v2 = T2[s2 * L + lane];
            float2 v3 = T2[s3 * L + lane];
            ax += (v0.x + v1.x) + (v2.x + v3.x);
            ay += (v0.y + v1.y) + (v2.y + v3.y);
        }
        for (; e < e1; ++e) {
            int s = ssrc[e];
            float2 v = T2[s * L + lane];
            ax += v.x;
            ay += v.y;
        }
        float ni = norm_in[wid];
        float2 b = reinterpret_cast<const float2*>(bias)[lane];
        float ox = ax * ni + b.x;
        float oy = ay * ni + b.y;
        if (RELU) { ox = fmaxf(ox, 0.f); oy = fmaxf(oy, 0.f); }
        reinterpret_cast<float2*>(out)[(size_t)wid * L + lane] = make_float2(ox, oy);
    }
}

// ---------------- launch ----------------
extern "C" void kernel_launch(void* const* d_in, const int* in_sizes, int n_in,
                              void* d_out, int out_size, void* d_ws, size_t ws_size,
                              hipStream_t stream) {
    const float* feat = (const float*)d_in[0];
    const int* src = (const int*)d_in[1];
    const int* dst = (const int*)d_in[2];
    const float* W0 = (const float*)d_in[3];
    const float* b0 = (const float*)d_in[4];
    const float* W1 = (const float*)d_in[5];
    const float* b1 = (const float*)d_in[6];
    const float* W2 = (const float*)d_in[7];
    const float* b2 = (const float*)d_in[8];
    float* outp = (float*)d_out;

    const int N = in_sizes[0] / KDIM;   // 100000
    const int E = in_sizes[1];          // 1600000
    const int nb = (N + 255) >> 8;      // 391 buckets (256 nodes each)
    const int nblkE = (E + EPB - 1) / EPB;  // 391 edge chunks

    auto align = [](size_t x) { return (x + 255) & ~(size_t)255; };
    char* p = (char*)d_ws;
    int* degO      = (int*)p;    p += align((size_t)N * 4);
    float* norm_in = (float*)p;  p += align((size_t)N * 4);
    int* row_off   = (int*)p;    p += align((size_t)(N + 1) * 4);
    int* gcntA     = (int*)p;    p += 512 * 4;              // contiguous with gcntB
    int* gcntB     = (int*)p;    p += 512 * 4;
    int* offA      = (int*)p;    p += align(513 * 4);
    int* offB      = (int*)p;    p += align(513 * 4);
    int* gcurA     = (int*)p;    p += align(512 * 4);
    int* gcurB     = (int*)p;    p += align(512 * 4);
    int* ssrc      = (int*)p;    p += align((size_t)E * 4);
    float* T       = (float*)p;  p += align((size_t)N * KDIM * 4);
    float* H       = (float*)p;  p += align((size_t)N * KDIM * 4);
    int* binA      = (int*)T;           // alias: T dead until first GEMM (B2 runs first)
    int* binB      = binA + E;          // 12.8MB total, fits in T's 51.2MB
    (void)n_in; (void)out_size; (void)ws_size;
    // total ~110.0MB < 110.8MB proven

    const int aggBlocks = (int)(((size_t)N * 64 + 255) / 256);  // wave per node

    // only the 4KB bucket-count block needs zeroing
    hipMemsetAsync(gcntA, 0, 1024 * 4, stream);

    b0_count<<<nblkE, 256, 0, stream>>>(src, dst, gcntA, gcntB, E, nb);
    b0b_offsets<<<1, 512, 0, stream>>>(gcntA, gcntB, offA, offB, gcurA, gcurB, row_off, nb, N, E);
    b1_bin<<<nblkE, 256, 0, stream>>>(src, dst, gcurA, gcurB, binA, binB, E, nb);
    b2_final<<<nb, 256, 0, stream>>>(binA, binB, offA, offB, ssrc, row_off, norm_in, degO, N);

    // layer 1: feat -> T -> H   (first GEMM overwrites bin area; B2 already consumed it)
    gemm_scaled<128, 32, 8><<<(N + 31) / 32, 256, 0, stream>>>(feat, degO, W0, T, N);
    agg_kernel<128, true><<<aggBlocks, 256, 0, stream>>>(T, row_off, ssrc, norm_in, b0, H, N);

    // layer 2: H -> T -> H
    gemm_scaled<128, 32, 8><<<(N + 31) / 32, 256, 0, stream>>>(H, degO, W1, T, N);
    agg_kernel<128, true><<<aggBlocks, 256, 0, stream>>>(T, row_off, ssrc, norm_in, b1, H, N);

    // layer 3: H -> T -> out (C=40)
    gemm_scaled<40, 64, 5><<<(N + 63) / 64, 256, 0, stream>>>(H, degO, W2, T, N);
    agg_kernel<40, false><<<aggBlocks, 256, 0, stream>>>(T, row_off, ssrc, norm_in, b2, outp, N);
}

// Round 7
// 591.215 us; speedup vs baseline: 1.4064x; 1.1301x over previous
//
#include <hip/hip_runtime.h>

// GCN: 3 x [ (norm_out .* X) @ W  ->  segment-sum over edges  ->  *norm_in + b -> relu ]
// N=100000, E=1600000, F=H=128, C=40.
// Round 7: bf16 T for layers 1-2 (halves gather bytes in the dominant agg kernels;
//          f32 accumulate; layer 3 fully f32). Build pipeline = round-6 proven, verbatim.

#define KDIM 128
#define EPB 4096   // edges per block in B0/B1 (16 per thread)

__device__ __forceinline__ float bf2f(unsigned short u) {
    unsigned int x = ((unsigned int)u) << 16;
    return __builtin_bit_cast(float, x);
}
__device__ __forceinline__ unsigned short f2bf(float f) {
    unsigned int x = __builtin_bit_cast(unsigned int, f);
    unsigned int r = x + 0x7FFFu + ((x >> 16) & 1u);   // RNE
    return (unsigned short)(r >> 16);
}

// ---------------- B0: bucket counts ----------------
__global__ __launch_bounds__(256) void b0_count(const int* __restrict__ src,
                                                const int* __restrict__ dst,
                                                int* __restrict__ gcntA,
                                                int* __restrict__ gcntB, int E, int nb) {
    __shared__ int hA[512], hB[512];
    const int t = threadIdx.x;
    for (int b = t; b < nb; b += 256) { hA[b] = 0; hB[b] = 0; }
    __syncthreads();
    const int base = blockIdx.x * EPB;
#pragma unroll
    for (int i = 0; i < 16; ++i) {
        int e = base + i * 256 + t;
        if (e < E) {
            atomicAdd(&hA[dst[e] >> 8], 1);
            atomicAdd(&hB[src[e] >> 8], 1);
        }
    }
    __syncthreads();
    for (int b = t; b < nb; b += 256) {
        if (hA[b]) atomicAdd(&gcntA[b], hA[b]);
        if (hB[b]) atomicAdd(&gcntB[b], hB[b]);
    }
}

// ---------------- B0b: exclusive scan of bucket counts -> offsets + cursors ----------------
__global__ __launch_bounds__(512) void b0b_offsets(const int* __restrict__ gcntA,
                                                   const int* __restrict__ gcntB,
                                                   int* __restrict__ offA,
                                                   int* __restrict__ offB,
                                                   int* __restrict__ gcurA,
                                                   int* __restrict__ gcurB,
                                                   int* __restrict__ row_off,
                                                   int nb, int N, int E) {
    __shared__ int sm[512];
    const int t = threadIdx.x;
    int v = (t < nb) ? gcntA[t] : 0;
    sm[t] = v;
    __syncthreads();
    for (int o = 1; o < 512; o <<= 1) {
        int x = (t >= o) ? sm[t - o] : 0;
        __syncthreads();
        sm[t] += x;
        __syncthreads();
    }
    if (t < nb) { offA[t + 1] = sm[t]; gcurA[t] = sm[t] - v; }
    if (t == 0) { offA[0] = 0; row_off[N] = E; }
    __syncthreads();
    int vb = (t < nb) ? gcntB[t] : 0;
    sm[t] = vb;
    __syncthreads();
    for (int o = 1; o < 512; o <<= 1) {
        int x = (t >= o) ? sm[t - o] : 0;
        __syncthreads();
        sm[t] += x;
        __syncthreads();
    }
    if (t < nb) { offB[t + 1] = sm[t]; gcurB[t] = sm[t] - vb; }
    if (t == 0) offB[0] = 0;
}

// ---------------- B1: bin edges into exact bucket regions ----------------
__global__ __launch_bounds__(256) void b1_bin(const int* __restrict__ src,
                                              const int* __restrict__ dst,
                                              int* __restrict__ gcurA,
                                              int* __restrict__ gcurB,
                                              int* __restrict__ binA,
                                              int* __restrict__ binB, int E, int nb) {
    __shared__ int hA[512], hB[512];
    const int t = threadIdx.x;
    for (int b = t; b < nb; b += 256) { hA[b] = 0; hB[b] = 0; }
    __syncthreads();
    const int base = blockIdx.x * EPB;
    int se[16], de[16];
#pragma unroll
    for (int i = 0; i < 16; ++i) {
        int e = base + i * 256 + t;
        se[i] = -1; de[i] = 0;
        if (e < E) {
            se[i] = src[e]; de[i] = dst[e];
            atomicAdd(&hA[de[i] >> 8], 1);
            atomicAdd(&hB[se[i] >> 8], 1);
        }
    }
    __syncthreads();
    for (int b = t; b < nb; b += 256) {
        int c = hA[b];
        hA[b] = c ? atomicAdd(&gcurA[b], c) : 0;
        c = hB[b];
        hB[b] = c ? atomicAdd(&gcurB[b], c) : 0;
    }
    __syncthreads();
#pragma unroll
    for (int i = 0; i < 16; ++i) {
        if (se[i] >= 0) {
            int pA = atomicAdd(&hA[de[i] >> 8], 1);
            binA[pA] = se[i] | ((de[i] & 255) << 17);     // src (17b) | dst-low (8b)
            int pB = atomicAdd(&hB[se[i] >> 8], 1);
            binB[pB] = se[i] & 255;
        }
    }
}

// ---------------- B2: per-bucket finalize ----------------
__global__ __launch_bounds__(256) void b2_final(const int* __restrict__ binA,
                                                const int* __restrict__ binB,
                                                const int* __restrict__ offA,
                                                const int* __restrict__ offB,
                                                int* __restrict__ ssrc,
                                                int* __restrict__ row_off,
                                                float* __restrict__ norm_in,
                                                int* __restrict__ degO, int N) {
    __shared__ int h[256], cur[256];
    const int b = blockIdx.x, t = threadIdx.x;
    const int nA0 = offA[b], cntA = offA[b + 1] - nA0;
    const int nodes = min(256, N - b * 256);

    h[t] = 0;
    __syncthreads();
    for (int k = t; k < cntA; k += 256) atomicAdd(&h[binA[nA0 + k] >> 17], 1);
    __syncthreads();

    int v = h[t];
    cur[t] = v;
    __syncthreads();
    for (int o = 1; o < 256; o <<= 1) {
        int x = (t >= o) ? cur[t - o] : 0;
        __syncthreads();
        cur[t] += x;
        __syncthreads();
    }
    const int rbase = nA0 + (cur[t] - v);
    if (t < nodes) {
        row_off[b * 256 + t] = rbase;
        norm_in[b * 256 + t] = (v > 0) ? rsqrtf((float)v) : 0.0f;
    }
    __syncthreads();
    cur[t] = rbase;
    __syncthreads();

    for (int k = t; k < cntA; k += 256) {
        int val = binA[nA0 + k];
        int pos = atomicAdd(&cur[val >> 17], 1);
        ssrc[pos] = val & 0x1FFFF;
    }

    __syncthreads();
    h[t] = 0;
    __syncthreads();
    const int nB0 = offB[b], cntB = offB[b + 1] - nB0;
    for (int k = t; k < cntB; k += 256) atomicAdd(&h[binB[nB0 + k]], 1);
    __syncthreads();
    if (t < nodes) degO[b * 256 + t] = h[t];
}

// ---------------- GEMM: T = (norm_out .* X) @ W ; OutT in {float, bf16(ushort)} ----------------
template <int M, int RPB, int CPT, bool BF16OUT>
__global__ __launch_bounds__(256) void gemm_scaled(const float* __restrict__ X,
                                                   const int* __restrict__ degO,
                                                   const float* __restrict__ W,
                                                   void* __restrict__ Tout, int nrows) {
    constexpr int CG = M / CPT;
    static_assert(CG * (RPB / 2) == 256, "thread mapping");
    __shared__ float xs[KDIM][RPB + 1];
    __shared__ float ws[64][M];

    const int t = threadIdx.x;
    const int rowbase = blockIdx.x * RPB;

    {
        constexpr int NV = RPB * (KDIM / 4) / 256;
        const float4* X4 = reinterpret_cast<const float4*>(X);
#pragma unroll
        for (int i = 0; i < NV; ++i) {
            int idx = t + i * 256;
            int rl = idx >> 5;
            int kq = idx & 31;
            int row = rowbase + rl;
            float4 v = make_float4(0.f, 0.f, 0.f, 0.f);
            float s = 0.f;
            if (row < nrows) {
                v = X4[(size_t)row * 32 + kq];
                int dv = degO[row];
                s = (dv > 0) ? rsqrtf((float)dv) : 0.0f;
            }
            xs[4 * kq + 0][rl] = v.x * s;
            xs[4 * kq + 1][rl] = v.y * s;
            xs[4 * kq + 2][rl] = v.z * s;
            xs[4 * kq + 3][rl] = v.w * s;
        }
    }

    const int rg = t / CG, cg = t % CG;
    const int r0 = 2 * rg, cb = cg * CPT;
    float acc0[CPT] = {0.f}, acc1[CPT] = {0.f};

    for (int kc = 0; kc < 2; ++kc) {
        __syncthreads();
        {
            constexpr int TOT4 = 64 * M / 4;
            const float4* W4 = reinterpret_cast<const float4*>(W);
            for (int i = t; i < TOT4; i += 256) {
                int kk = i / (M / 4), m4 = i % (M / 4);
                float4 v = W4[(size_t)(kc * 64 + kk) * (M / 4) + m4];
                ws[kk][4 * m4 + 0] = v.x;
                ws[kk][4 * m4 + 1] = v.y;
                ws[kk][4 * m4 + 2] = v.z;
                ws[kk][4 * m4 + 3] = v.w;
            }
        }
        __syncthreads();
#pragma unroll 8
        for (int k = 0; k < 64; ++k) {
            float xv0 = xs[kc * 64 + k][r0];
            float xv1 = xs[kc * 64 + k][r0 + 1];
#pragma unroll
            for (int j = 0; j < CPT; ++j) {
                float wv = ws[k][cb + j];
                acc0[j] = fmaf(xv0, wv, acc0[j]);
                acc1[j] = fmaf(xv1, wv, acc1[j]);
            }
        }
    }

    int row0 = rowbase + r0;
    if constexpr (BF16OUT) {
        static_assert(CPT == 8, "bf16 path packs 8");
        unsigned short* Tb = (unsigned short*)Tout;
        if (row0 < nrows) {
            uint4 pk;
            pk.x = f2bf(acc0[0]) | ((unsigned)f2bf(acc0[1]) << 16);
            pk.y = f2bf(acc0[2]) | ((unsigned)f2bf(acc0[3]) << 16);
            pk.z = f2bf(acc0[4]) | ((unsigned)f2bf(acc0[5]) << 16);
            pk.w = f2bf(acc0[6]) | ((unsigned)f2bf(acc0[7]) << 16);
            *reinterpret_cast<uint4*>(&Tb[(size_t)row0 * M + cb]) = pk;
        }
        if (row0 + 1 < nrows) {
            uint4 pk;
            pk.x = f2bf(acc1[0]) | ((unsigned)f2bf(acc1[1]) << 16);
            pk.y = f2bf(acc1[2]) | ((unsigned)f2bf(acc1[3]) << 16);
            pk.z = f2bf(acc1[4]) | ((unsigned)f2bf(acc1[5]) << 16);
            pk.w = f2bf(acc1[6]) | ((unsigned)f2bf(acc1[7]) << 16);
            *reinterpret_cast<uint4*>(&Tb[(size_t)(row0 + 1) * M + cb]) = pk;
        }
    } else {
        float* T = (float*)Tout;
        if (row0 < nrows) {
#pragma unroll
            for (int j = 0; j < CPT; ++j) T[(size_t)row0 * M + cb + j] = acc0[j];
        }
        if (row0 + 1 < nrows) {
#pragma unroll
            for (int j = 0; j < CPT; ++j) T[(size_t)(row0 + 1) * M + cb + j] = acc1[j];
        }
    }
}

// ---------------- aggregation over bf16 T (layers 1-2): 64 lanes x ushort2 ----------------
__global__ __launch_bounds__(256) void agg_bf16(const unsigned short* __restrict__ Tb,
                                                const int* __restrict__ row_off,
                                                const int* __restrict__ ssrc,
                                                const float* __restrict__ norm_in,
                                                const float* __restrict__ bias,
                                                float* __restrict__ out, int n) {
    const int wid = (int)((blockIdx.x * blockDim.x + threadIdx.x) >> 6);
    const int lane = threadIdx.x & 63;
    if (wid >= n) return;
    const uint* T2 = reinterpret_cast<const uint*>(Tb);   // row = 64 uints (128 bf16)
    const int e0 = row_off[wid], e1 = row_off[wid + 1];
    float ax = 0.f, ay = 0.f;
    int e = e0;
    for (; e + 4 <= e1; e += 4) {
        int s0 = ssrc[e], s1 = ssrc[e + 1], s2 = ssrc[e + 2], s3 = ssrc[e + 3];
        uint v0 = T2[(size_t)s0 * 64 + lane];
        uint v1 = T2[(size_t)s1 * 64 + lane];
        uint v2 = T2[(size_t)s2 * 64 + lane];
        uint v3 = T2[(size_t)s3 * 64 + lane];
        ax += bf2f((unsigned short)v0) + bf2f((unsigned short)v1)
            + bf2f((unsigned short)v2) + bf2f((unsigned short)v3);
        ay += bf2f((unsigned short)(v0 >> 16)) + bf2f((unsigned short)(v1 >> 16))
            + bf2f((unsigned short)(v2 >> 16)) + bf2f((unsigned short)(v3 >> 16));
    }
    for (; e < e1; ++e) {
        uint v = T2[(size_t)ssrc[e] * 64 + lane];
        ax += bf2f((unsigned short)v);
        ay += bf2f((unsigned short)(v >> 16));
    }
    float ni = norm_in[wid];
    float2 b = reinterpret_cast<const float2*>(bias)[lane];
    float ox = fmaxf(ax * ni + b.x, 0.f);   // layers 1-2 always relu
    float oy = fmaxf(ay * ni + b.y, 0.f);
    reinterpret_cast<float2*>(out)[(size_t)wid * 64 + lane] = make_float2(ox, oy);
}

// ---------------- aggregation f32 (layer 3, round-1/5/6 proven, verbatim) ----------------
template <int M, bool RELU>
__global__ __launch_bounds__(256) void agg_kernel(const float* __restrict__ T,
                                                  const int* __restrict__ row_off,
                                                  const int* __restrict__ ssrc,
                                                  const float* __restrict__ norm_in,
                                                  const float* __restrict__ bias,
                                                  float* __restrict__ out, int n) {
    const int wid = (int)((blockIdx.x * blockDim.x + threadIdx.x) >> 6);
    const int lane = threadIdx.x & 63;
    if (wid >= n) return;
    constexpr int L = M / 2;
    const float2* T2 = reinterpret_cast<const float2*>(T);
    const int e0 = row_off[wid], e1 = row_off[wid + 1];
    if (lane < L) {
        float ax = 0.f, ay = 0.f;
        int e = e0;
        for (; e + 4 <= e1; e += 4) {
            int s0 = ssrc[e], s1 = ssrc[e + 1], s2 = ssrc[e + 2], s3 = ssrc[e + 3];
            float2 v0 = T2[s0 * L + lane];
            float2 v1 = T2[s1 * L + lane];
            float2 v2 = T2[s2 * L + lane];
            float2 v3 = T2[s3 * L + lane];
            ax += (v0.x + v1.x) + (v2.x + v3.x);
            ay += (v0.y + v1.y) + (v2.y + v3.y);
        }
        for (; e < e1; ++e) {
            int s = ssrc[e];
            float2 v = T2[s * L + lane];
            ax += v.x;
            ay += v.y;
        }
        float ni = norm_in[wid];
        float2 b = reinterpret_cast<const float2*>(bias)[lane];
        float ox = ax * ni + b.x;
        float oy = ay * ni + b.y;
        if (RELU) { ox = fmaxf(ox, 0.f); oy = fmaxf(oy, 0.f); }
        reinterpret_cast<float2*>(out)[(size_t)wid * L + lane] = make_float2(ox, oy);
    }
}

// ---------------- launch ----------------
extern "C" void kernel_launch(void* const* d_in, const int* in_sizes, int n_in,
                              void* d_out, int out_size, void* d_ws, size_t ws_size,
                              hipStream_t stream) {
    const float* feat = (const float*)d_in[0];
    const int* src = (const int*)d_in[1];
    const int* dst = (const int*)d_in[2];
    const float* W0 = (const float*)d_in[3];
    const float* b0 = (const float*)d_in[4];
    const float* W1 = (const float*)d_in[5];
    const float* b1 = (const float*)d_in[6];
    const float* W2 = (const float*)d_in[7];
    const float* b2 = (const float*)d_in[8];
    float* outp = (float*)d_out;

    const int N = in_sizes[0] / KDIM;   // 100000
    const int E = in_sizes[1];          // 1600000
    const int nb = (N + 255) >> 8;      // 391 buckets
    const int nblkE = (E + EPB - 1) / EPB;

    auto align = [](size_t x) { return (x + 255) & ~(size_t)255; };
    char* p = (char*)d_ws;
    int* degO      = (int*)p;    p += align((size_t)N * 4);
    float* norm_in = (float*)p;  p += align((size_t)N * 4);
    int* row_off   = (int*)p;    p += align((size_t)(N + 1) * 4);
    int* gcntA     = (int*)p;    p += 512 * 4;
    int* gcntB     = (int*)p;    p += 512 * 4;
    int* offA      = (int*)p;    p += align(513 * 4);
    int* offB      = (int*)p;    p += align(513 * 4);
    int* gcurA     = (int*)p;    p += align(512 * 4);
    int* gcurB     = (int*)p;    p += align(512 * 4);
    int* ssrc      = (int*)p;    p += align((size_t)E * 4);
    float* T       = (float*)p;  p += align((size_t)N * KDIM * 4);
    float* H       = (float*)p;  p += align((size_t)N * KDIM * 4);
    unsigned short* Tb = (unsigned short*)T;   // bf16 alias (uses half of T's area)
    int* binA      = (int*)T;                  // B1/B2 alias, dead before first GEMM
    int* binB      = binA + E;
    (void)n_in; (void)out_size; (void)ws_size;

    const int aggBlocks = (int)(((size_t)N * 64 + 255) / 256);

    hipMemsetAsync(gcntA, 0, 1024 * 4, stream);

    b0_count<<<nblkE, 256, 0, stream>>>(src, dst, gcntA, gcntB, E, nb);
    b0b_offsets<<<1, 512, 0, stream>>>(gcntA, gcntB, offA, offB, gcurA, gcurB, row_off, nb, N, E);
    b1_bin<<<nblkE, 256, 0, stream>>>(src, dst, gcurA, gcurB, binA, binB, E, nb);
    b2_final<<<nb, 256, 0, stream>>>(binA, binB, offA, offB, ssrc, row_off, norm_in, degO, N);

    // layer 1: feat -> Tb (bf16) -> H
    gemm_scaled<128, 32, 8, true><<<(N + 31) / 32, 256, 0, stream>>>(feat, degO, W0, Tb, N);
    agg_bf16<<<aggBlocks, 256, 0, stream>>>(Tb, row_off, ssrc, norm_in, b0, H, N);

    // layer 2: H -> Tb (bf16) -> H
    gemm_scaled<128, 32, 8, true><<<(N + 31) / 32, 256, 0, stream>>>(H, degO, W1, Tb, N);
    agg_bf16<<<aggBlocks, 256, 0, stream>>>(Tb, row_off, ssrc, norm_in, b1, H, N);

    // layer 3: H -> T (f32) -> out (C=40)
    gemm_scaled<40, 64, 5, false><<<(N + 63) / 64, 256, 0, stream>>>(H, degO, W2, T, N);
    agg_kernel<40, false><<<aggBlocks, 256, 0, stream>>>(T, row_off, ssrc, norm_in, b2, outp, N);
}

// Round 9
// 535.092 us; speedup vs baseline: 1.5540x; 1.1049x over previous
//
#include <hip/hip_runtime.h>

// GCN: 3 x [ (norm_out .* X) @ W  ->  segment-sum over edges  ->  *norm_in + b -> relu ]
// N=100000, E=1600000, F=H=128, C=40.
// Round 8 (resubmit; round-8 bench was an infra timeout, kernel never ran):
//   layers 1-2 GEMM -> MFMA bf16 (16x16x32), A-fragments direct from global
//   (coalesced 8KB/wave), W pre-transposed to bf16 + LDS-staged (padded, 2-way max).
//   Layer 3 + aggs + build pipeline = round-7 proven, verbatim.

#define KDIM 128
#define EPB 4096

typedef __attribute__((ext_vector_type(4))) float f32x4;
typedef __attribute__((ext_vector_type(8))) short short8;

__device__ __forceinline__ float bf2f(unsigned short u) {
    unsigned int x = ((unsigned int)u) << 16;
    return __builtin_bit_cast(float, x);
}
__device__ __forceinline__ unsigned short f2bf(float f) {
    unsigned int x = __builtin_bit_cast(unsigned int, f);
    unsigned int r = x + 0x7FFFu + ((x >> 16) & 1u);   // RNE
    return (unsigned short)(r >> 16);
}

// ---------------- B0: bucket counts ----------------
__global__ __launch_bounds__(256) void b0_count(const int* __restrict__ src,
                                                const int* __restrict__ dst,
                                                int* __restrict__ gcntA,
                                                int* __restrict__ gcntB, int E, int nb) {
    __shared__ int hA[512], hB[512];
    const int t = threadIdx.x;
    for (int b = t; b < nb; b += 256) { hA[b] = 0; hB[b] = 0; }
    __syncthreads();
    const int base = blockIdx.x * EPB;
#pragma unroll
    for (int i = 0; i < 16; ++i) {
        int e = base + i * 256 + t;
        if (e < E) {
            atomicAdd(&hA[dst[e] >> 8], 1);
            atomicAdd(&hB[src[e] >> 8], 1);
        }
    }
    __syncthreads();
    for (int b = t; b < nb; b += 256) {
        if (hA[b]) atomicAdd(&gcntA[b], hA[b]);
        if (hB[b]) atomicAdd(&gcntB[b], hB[b]);
    }
}

// ---------------- B0b: bucket offsets ----------------
__global__ __launch_bounds__(512) void b0b_offsets(const int* __restrict__ gcntA,
                                                   const int* __restrict__ gcntB,
                                                   int* __restrict__ offA,
                                                   int* __restrict__ offB,
                                                   int* __restrict__ gcurA,
                                                   int* __restrict__ gcurB,
                                                   int* __restrict__ row_off,
                                                   int nb, int N, int E) {
    __shared__ int sm[512];
    const int t = threadIdx.x;
    int v = (t < nb) ? gcntA[t] : 0;
    sm[t] = v;
    __syncthreads();
    for (int o = 1; o < 512; o <<= 1) {
        int x = (t >= o) ? sm[t - o] : 0;
        __syncthreads();
        sm[t] += x;
        __syncthreads();
    }
    if (t < nb) { offA[t + 1] = sm[t]; gcurA[t] = sm[t] - v; }
    if (t == 0) { offA[0] = 0; row_off[N] = E; }
    __syncthreads();
    int vb = (t < nb) ? gcntB[t] : 0;
    sm[t] = vb;
    __syncthreads();
    for (int o = 1; o < 512; o <<= 1) {
        int x = (t >= o) ? sm[t - o] : 0;
        __syncthreads();
        sm[t] += x;
        __syncthreads();
    }
    if (t < nb) { offB[t + 1] = sm[t]; gcurB[t] = sm[t] - vb; }
    if (t == 0) offB[0] = 0;
}

// ---------------- B1: bin edges ----------------
__global__ __launch_bounds__(256) void b1_bin(const int* __restrict__ src,
                                              const int* __restrict__ dst,
                                              int* __restrict__ gcurA,
                                              int* __restrict__ gcurB,
                                              int* __restrict__ binA,
                                              int* __restrict__ binB, int E, int nb) {
    __shared__ int hA[512], hB[512];
    const int t = threadIdx.x;
    for (int b = t; b < nb; b += 256) { hA[b] = 0; hB[b] = 0; }
    __syncthreads();
    const int base = blockIdx.x * EPB;
    int se[16], de[16];
#pragma unroll
    for (int i = 0; i < 16; ++i) {
        int e = base + i * 256 + t;
        se[i] = -1; de[i] = 0;
        if (e < E) {
            se[i] = src[e]; de[i] = dst[e];
            atomicAdd(&hA[de[i] >> 8], 1);
            atomicAdd(&hB[se[i] >> 8], 1);
        }
    }
    __syncthreads();
    for (int b = t; b < nb; b += 256) {
        int c = hA[b];
        hA[b] = c ? atomicAdd(&gcurA[b], c) : 0;
        c = hB[b];
        hB[b] = c ? atomicAdd(&gcurB[b], c) : 0;
    }
    __syncthreads();
#pragma unroll
    for (int i = 0; i < 16; ++i) {
        if (se[i] >= 0) {
            int pA = atomicAdd(&hA[de[i] >> 8], 1);
            binA[pA] = se[i] | ((de[i] & 255) << 17);
            int pB = atomicAdd(&hB[se[i] >> 8], 1);
            binB[pB] = se[i] & 255;
        }
    }
}

// ---------------- B2: per-bucket finalize ----------------
__global__ __launch_bounds__(256) void b2_final(const int* __restrict__ binA,
                                                const int* __restrict__ binB,
                                                const int* __restrict__ offA,
                                                const int* __restrict__ offB,
                                                int* __restrict__ ssrc,
                                                int* __restrict__ row_off,
                                                float* __restrict__ norm_in,
                                                int* __restrict__ degO, int N) {
    __shared__ int h[256], cur[256];
    const int b = blockIdx.x, t = threadIdx.x;
    const int nA0 = offA[b], cntA = offA[b + 1] - nA0;
    const int nodes = min(256, N - b * 256);

    h[t] = 0;
    __syncthreads();
    for (int k = t; k < cntA; k += 256) atomicAdd(&h[binA[nA0 + k] >> 17], 1);
    __syncthreads();

    int v = h[t];
    cur[t] = v;
    __syncthreads();
    for (int o = 1; o < 256; o <<= 1) {
        int x = (t >= o) ? cur[t - o] : 0;
        __syncthreads();
        cur[t] += x;
        __syncthreads();
    }
    const int rbase = nA0 + (cur[t] - v);
    if (t < nodes) {
        row_off[b * 256 + t] = rbase;
        norm_in[b * 256 + t] = (v > 0) ? rsqrtf((float)v) : 0.0f;
    }
    __syncthreads();
    cur[t] = rbase;
    __syncthreads();

    for (int k = t; k < cntA; k += 256) {
        int val = binA[nA0 + k];
        int pos = atomicAdd(&cur[val >> 17], 1);
        ssrc[pos] = val & 0x1FFFF;
    }

    __syncthreads();
    h[t] = 0;
    __syncthreads();
    const int nB0 = offB[b], cntB = offB[b + 1] - nB0;
    for (int k = t; k < cntB; k += 256) atomicAdd(&h[binB[nB0 + k]], 1);
    __syncthreads();
    if (t < nodes) degO[b * 256 + t] = h[t];
}

// ---------------- prep: W (128x128 f32, k-major) -> Wtg (c-major bf16 pairs) ----------------
__global__ __launch_bounds__(256) void prep_w(const float* __restrict__ W,
                                              unsigned int* __restrict__ Wtg) {
    int idx = blockIdx.x * 256 + threadIdx.x;   // 8192 dwords = 128 c x 64 k-pairs
    if (idx < 8192) {
        int c = idx >> 6, kk = idx & 63;
        unsigned short lo = f2bf(W[(2 * kk) * 128 + c]);
        unsigned short hi = f2bf(W[(2 * kk + 1) * 128 + c]);
        Wtg[idx] = (unsigned)lo | ((unsigned)hi << 16);
    }
}

// ---------------- MFMA GEMM: Tb = bf16( (norm_out .* X) @ W ), 128x128 ----------------
// Wave owns a 16-row x 128-col tile. A frags direct from global (coalesced), B from LDS.
// Layouts (m89/m92 verified): A row=l&15, B col=l&15, k=(l>>4)*8+j; D col=l&15, row=(l>>4)*4+reg.
__global__ __launch_bounds__(256, 4) void gemm_mfma(const float* __restrict__ X,
                                                    const int* __restrict__ degO,
                                                    const unsigned int* __restrict__ Wtg,
                                                    unsigned short* __restrict__ Tb,
                                                    int ntiles, int gridWaves) {
    __shared__ unsigned int Wt[128 * 68];   // [c][k-pair], 68 dwords/row (64 + 4 pad)
    const int t = threadIdx.x;
    for (int idx = t; idx < 128 * 64; idx += 256) {
        int c = idx >> 6, kk = idx & 63;
        Wt[c * 68 + kk] = Wtg[idx];
    }
    __syncthreads();

    const int lane = t & 63;
    const int w = t >> 6;
    const int l15 = lane & 15;
    const int lh = lane >> 4;    // 0..3
    const unsigned short* Wts = reinterpret_cast<const unsigned short*>(Wt);
    const float4* X4 = reinterpret_cast<const float4*>(X);

    for (int tile = blockIdx.x * 4 + w; tile < ntiles; tile += gridWaves) {
        const int row = tile * 16 + l15;
        const int dv = degO[row];
        const float s = (dv > 0) ? rsqrtf((float)dv) : 0.0f;
        const float4* Xr = X4 + ((size_t)row * 32 + lh * 2);

        f32x4 acc[8];
#pragma unroll
        for (int ct = 0; ct < 8; ++ct) acc[ct] = f32x4{0.f, 0.f, 0.f, 0.f};

#pragma unroll
        for (int kc = 0; kc < 4; ++kc) {
            float4 a0 = Xr[kc * 8];        // k0 = kc*32 + lh*8
            float4 a1 = Xr[kc * 8 + 1];
            short8 af;
            af[0] = (short)f2bf(a0.x * s); af[1] = (short)f2bf(a0.y * s);
            af[2] = (short)f2bf(a0.z * s); af[3] = (short)f2bf(a0.w * s);
            af[4] = (short)f2bf(a1.x * s); af[5] = (short)f2bf(a1.y * s);
            af[6] = (short)f2bf(a1.z * s); af[7] = (short)f2bf(a1.w * s);
            const int k0 = kc * 32 + lh * 8;
#pragma unroll
            for (int ct = 0; ct < 8; ++ct) {
                short8 bf = *reinterpret_cast<const short8*>(&Wts[(ct * 16 + l15) * 136 + k0]);
                acc[ct] = __builtin_amdgcn_mfma_f32_16x16x32_bf16(af, bf, acc[ct], 0, 0, 0);
            }
        }

        const int rbase = tile * 16 + lh * 4;
#pragma unroll
        for (int ct = 0; ct < 8; ++ct) {
            const int col = ct * 16 + l15;
#pragma unroll
            for (int r = 0; r < 4; ++r)
                Tb[(size_t)(rbase + r) * 128 + col] = f2bf(acc[ct][r]);
        }
    }
}

// ---------------- aggregation over bf16 T (layers 1-2) ----------------
__global__ __launch_bounds__(256) void agg_bf16(const unsigned short* __restrict__ Tb,
                                                const int* __restrict__ row_off,
                                                const int* __restrict__ ssrc,
                                                const float* __restrict__ norm_in,
                                                const float* __restrict__ bias,
                                                float* __restrict__ out, int n) {
    const int wid = (int)((blockIdx.x * blockDim.x + threadIdx.x) >> 6);
    const int lane = threadIdx.x & 63;
    if (wid >= n) return;
    const uint* T2 = reinterpret_cast<const uint*>(Tb);
    const int e0 = row_off[wid], e1 = row_off[wid + 1];
    float ax = 0.f, ay = 0.f;
    int e = e0;
    for (; e + 4 <= e1; e += 4) {
        int s0 = ssrc[e], s1 = ssrc[e + 1], s2 = ssrc[e + 2], s3 = ssrc[e + 3];
        uint v0 = T2[(size_t)s0 * 64 + lane];
        uint v1 = T2[(size_t)s1 * 64 + lane];
        uint v2 = T2[(size_t)s2 * 64 + lane];
        uint v3 = T2[(size_t)s3 * 64 + lane];
        ax += bf2f((unsigned short)v0) + bf2f((unsigned short)v1)
            + bf2f((unsigned short)v2) + bf2f((unsigned short)v3);
        ay += bf2f((unsigned short)(v0 >> 16)) + bf2f((unsigned short)(v1 >> 16))
            + bf2f((unsigned short)(v2 >> 16)) + bf2f((unsigned short)(v3 >> 16));
    }
    for (; e < e1; ++e) {
        uint v = T2[(size_t)ssrc[e] * 64 + lane];
        ax += bf2f((unsigned short)v);
        ay += bf2f((unsigned short)(v >> 16));
    }
    float ni = norm_in[wid];
    float2 b = reinterpret_cast<const float2*>(bias)[lane];
    float ox = fmaxf(ax * ni + b.x, 0.f);
    float oy = fmaxf(ay * ni + b.y, 0.f);
    reinterpret_cast<float2*>(out)[(size_t)wid * 64 + lane] = make_float2(ox, oy);
}

// ---------------- GEMM f32 (layer 3 only, proven) ----------------
template <int M, int RPB, int CPT>
__global__ __launch_bounds__(256) void gemm_scaled(const float* __restrict__ X,
                                                   const int* __restrict__ degO,
                                                   const float* __restrict__ W,
                                                   float* __restrict__ T, int nrows) {
    constexpr int CG = M / CPT;
    static_assert(CG * (RPB / 2) == 256, "thread mapping");
    __shared__ float xs[KDIM][RPB + 1];
    __shared__ float ws[64][M];

    const int t = threadIdx.x;
    const int rowbase = blockIdx.x * RPB;

    {
        constexpr int NV = RPB * (KDIM / 4) / 256;
        const float4* X4 = reinterpret_cast<const float4*>(X);
#pragma unroll
        for (int i = 0; i < NV; ++i) {
            int idx = t + i * 256;
            int rl = idx >> 5;
            int kq = idx & 31;
            int row = rowbase + rl;
            float4 v = make_float4(0.f, 0.f, 0.f, 0.f);
            float s = 0.f;
            if (row < nrows) {
                v = X4[(size_t)row * 32 + kq];
                int dv = degO[row];
                s = (dv > 0) ? rsqrtf((float)dv) : 0.0f;
            }
            xs[4 * kq + 0][rl] = v.x * s;
            xs[4 * kq + 1][rl] = v.y * s;
            xs[4 * kq + 2][rl] = v.z * s;
            xs[4 * kq + 3][rl] = v.w * s;
        }
    }

    const int rg = t / CG, cg = t % CG;
    const int r0 = 2 * rg, cb = cg * CPT;
    float acc0[CPT] = {0.f}, acc1[CPT] = {0.f};

    for (int kc = 0; kc < 2; ++kc) {
        __syncthreads();
        {
            constexpr int TOT4 = 64 * M / 4;
            const float4* W4 = reinterpret_cast<const float4*>(W);
            for (int i = t; i < TOT4; i += 256) {
                int kk = i / (M / 4), m4 = i % (M / 4);
                float4 v = W4[(size_t)(kc * 64 + kk) * (M / 4) + m4];
                ws[kk][4 * m4 + 0] = v.x;
                ws[kk][4 * m4 + 1] = v.y;
                ws[kk][4 * m4 + 2] = v.z;
                ws[kk][4 * m4 + 3] = v.w;
            }
        }
        __syncthreads();
#pragma unroll 8
        for (int k = 0; k < 64; ++k) {
            float xv0 = xs[kc * 64 + k][r0];
            float xv1 = xs[kc * 64 + k][r0 + 1];
#pragma unroll
            for (int j = 0; j < CPT; ++j) {
                float wv = ws[k][cb + j];
                acc0[j] = fmaf(xv0, wv, acc0[j]);
                acc1[j] = fmaf(xv1, wv, acc1[j]);
            }
        }
    }

    int row0 = rowbase + r0;
    if (row0 < nrows) {
#pragma unroll
        for (int j = 0; j < CPT; ++j) T[(size_t)row0 * M + cb + j] = acc0[j];
    }
    if (row0 + 1 < nrows) {
#pragma unroll
        for (int j = 0; j < CPT; ++j) T[(size_t)(row0 + 1) * M + cb + j] = acc1[j];
    }
}

// ---------------- aggregation f32 (layer 3, proven) ----------------
template <int M, bool RELU>
__global__ __launch_bounds__(256) void agg_kernel(const float* __restrict__ T,
                                                  const int* __restrict__ row_off,
                                                  const int* __restrict__ ssrc,
                                                  const float* __restrict__ norm_in,
                                                  const float* __restrict__ bias,
                                                  float* __restrict__ out, int n) {
    const int wid = (int)((blockIdx.x * blockDim.x + threadIdx.x) >> 6);
    const int lane = threadIdx.x & 63;
    if (wid >= n) return;
    constexpr int L = M / 2;
    const float2* T2 = reinterpret_cast<const float2*>(T);
    const int e0 = row_off[wid], e1 = row_off[wid + 1];
    if (lane < L) {
        float ax = 0.f, ay = 0.f;
        int e = e0;
        for (; e + 4 <= e1; e += 4) {
            int s0 = ssrc[e], s1 = ssrc[e + 1], s2 = ssrc[e + 2], s3 = ssrc[e + 3];
            float2 v0 = T2[s0 * L + lane];
            float2 v1 = T2[s1 * L + lane];
            float2 v2 = T2[s2 * L + lane];
            float2 v3 = T2[s3 * L + lane];
            ax += (v0.x + v1.x) + (v2.x + v3.x);
            ay += (v0.y + v1.y) + (v2.y + v3.y);
        }
        for (; e < e1; ++e) {
            int s = ssrc[e];
            float2 v = T2[s * L + lane];
            ax += v.x;
            ay += v.y;
        }
        float ni = norm_in[wid];
        float2 b = reinterpret_cast<const float2*>(bias)[lane];
        float ox = ax * ni + b.x;
        float oy = ay * ni + b.y;
        if (RELU) { ox = fmaxf(ox, 0.f); oy = fmaxf(oy, 0.f); }
        reinterpret_cast<float2*>(out)[(size_t)wid * L + lane] = make_float2(ox, oy);
    }
}

// ---------------- launch ----------------
extern "C" void kernel_launch(void* const* d_in, const int* in_sizes, int n_in,
                              void* d_out, int out_size, void* d_ws, size_t ws_size,
                              hipStream_t stream) {
    const float* feat = (const float*)d_in[0];
    const int* src = (const int*)d_in[1];
    const int* dst = (const int*)d_in[2];
    const float* W0 = (const float*)d_in[3];
    const float* b0 = (const float*)d_in[4];
    const float* W1 = (const float*)d_in[5];
    const float* b1 = (const float*)d_in[6];
    const float* W2 = (const float*)d_in[7];
    const float* b2 = (const float*)d_in[8];
    float* outp = (float*)d_out;

    const int N = in_sizes[0] / KDIM;   // 100000
    const int E = in_sizes[1];          // 1600000
    const int nb = (N + 255) >> 8;
    const int nblkE = (E + EPB - 1) / EPB;

    auto align = [](size_t x) { return (x + 255) & ~(size_t)255; };
    char* p = (char*)d_ws;
    int* degO      = (int*)p;    p += align((size_t)N * 4);
    float* norm_in = (float*)p;  p += align((size_t)N * 4);
    int* row_off   = (int*)p;    p += align((size_t)(N + 1) * 4);
    int* gcntA     = (int*)p;    p += 512 * 4;
    int* gcntB     = (int*)p;    p += 512 * 4;
    int* offA      = (int*)p;    p += align(513 * 4);
    int* offB      = (int*)p;    p += align(513 * 4);
    int* gcurA     = (int*)p;    p += align(512 * 4);
    int* gcurB     = (int*)p;    p += align(512 * 4);
    unsigned int* W0t = (unsigned int*)p;  p += align(8192 * 4);
    unsigned int* W1t = (unsigned int*)p;  p += align(8192 * 4);
    int* ssrc      = (int*)p;    p += align((size_t)E * 4);
    float* T       = (float*)p;  p += align((size_t)N * KDIM * 4);
    float* H       = (float*)p;  p += align((size_t)N * KDIM * 4);
    unsigned short* Tb = (unsigned short*)T;
    int* binA      = (int*)T;
    int* binB      = binA + E;
    (void)n_in; (void)out_size; (void)ws_size;

    const int aggBlocks = (int)(((size_t)N * 64 + 255) / 256);
    const int ntiles = N / 16;                      // 6250 (N % 16 == 0)
    const int gBlocks = (ntiles + 3) / 4;           // 1563, one tile per wave
    const int gridWaves = gBlocks * 4;

    hipMemsetAsync(gcntA, 0, 1024 * 4, stream);

    prep_w<<<32, 256, 0, stream>>>(W0, W0t);
    prep_w<<<32, 256, 0, stream>>>(W1, W1t);

    b0_count<<<nblkE, 256, 0, stream>>>(src, dst, gcntA, gcntB, E, nb);
    b0b_offsets<<<1, 512, 0, stream>>>(gcntA, gcntB, offA, offB, gcurA, gcurB, row_off, nb, N, E);
    b1_bin<<<nblkE, 256, 0, stream>>>(src, dst, gcurA, gcurB, binA, binB, E, nb);
    b2_final<<<nb, 256, 0, stream>>>(binA, binB, offA, offB, ssrc, row_off, norm_in, degO, N);

    // layer 1: feat -> Tb (bf16, MFMA) -> H
    gemm_mfma<<<gBlocks, 256, 0, stream>>>(feat, degO, W0t, Tb, ntiles, gridWaves);
    agg_bf16<<<aggBlocks, 256, 0, stream>>>(Tb, row_off, ssrc, norm_in, b0, H, N);

    // layer 2: H -> Tb (bf16, MFMA) -> H
    gemm_mfma<<<gBlocks, 256, 0, stream>>>(H, degO, W1t, Tb, ntiles, gridWaves);
    agg_bf16<<<aggBlocks, 256, 0, stream>>>(Tb, row_off, ssrc, norm_in, b1, H, N);

    // layer 3: H -> T (f32) -> out (C=40)
    gemm_scaled<40, 64, 5><<<(N + 63) / 64, 256, 0, stream>>>(H, degO, W2, T, N);
    agg_kernel<40, false><<<aggBlocks, 256, 0, stream>>>(T, row_off, ssrc, norm_in, b2, outp, N);
}

// Round 12
// 500.106 us; speedup vs baseline: 1.6627x; 1.0700x over previous
//
#include <hip/hip_runtime.h>

// GCN: 3 x [ (norm_out .* X) @ W  ->  segment-sum over edges  ->  *norm_in + b -> relu ]
// N=100000, E=1600000, F=H=128, C=40.
// Round 12 = round 10 with the agg_f3 stride bug fixed:
//   T3 row = 64 bf16 = 16 uint2 -> T3q[s*16 + j]  (was s*32 + j*2: wrong row AND col).
// Everything else identical to round-10/11 source (layers 1-2 = round-9 proven).

#define KDIM 128
#define EPB 4096

typedef __attribute__((ext_vector_type(4))) float f32x4;
typedef __attribute__((ext_vector_type(8))) short short8;

__device__ __forceinline__ float bf2f(unsigned short u) {
    unsigned int x = ((unsigned int)u) << 16;
    return __builtin_bit_cast(float, x);
}
__device__ __forceinline__ unsigned short f2bf(float f) {
    unsigned int x = __builtin_bit_cast(unsigned int, f);
    unsigned int r = x + 0x7FFFu + ((x >> 16) & 1u);   // RNE
    return (unsigned short)(r >> 16);
}

// ---------------- B0: bucket counts ----------------
__global__ __launch_bounds__(256) void b0_count(const int* __restrict__ src,
                                                const int* __restrict__ dst,
                                                int* __restrict__ gcntA,
                                                int* __restrict__ gcntB, int E, int nb) {
    __shared__ int hA[512], hB[512];
    const int t = threadIdx.x;
    for (int b = t; b < nb; b += 256) { hA[b] = 0; hB[b] = 0; }
    __syncthreads();
    const int base = blockIdx.x * EPB;
#pragma unroll
    for (int i = 0; i < 16; ++i) {
        int e = base + i * 256 + t;
        if (e < E) {
            atomicAdd(&hA[dst[e] >> 8], 1);
            atomicAdd(&hB[src[e] >> 8], 1);
        }
    }
    __syncthreads();
    for (int b = t; b < nb; b += 256) {
        if (hA[b]) atomicAdd(&gcntA[b], hA[b]);
        if (hB[b]) atomicAdd(&gcntB[b], hB[b]);
    }
}

// ---------------- B0b: bucket offsets ----------------
__global__ __launch_bounds__(512) void b0b_offsets(const int* __restrict__ gcntA,
                                                   const int* __restrict__ gcntB,
                                                   int* __restrict__ offA,
                                                   int* __restrict__ offB,
                                                   int* __restrict__ gcurA,
                                                   int* __restrict__ gcurB,
                                                   int* __restrict__ row_off,
                                                   int nb, int N, int E) {
    __shared__ int sm[512];
    const int t = threadIdx.x;
    int v = (t < nb) ? gcntA[t] : 0;
    sm[t] = v;
    __syncthreads();
    for (int o = 1; o < 512; o <<= 1) {
        int x = (t >= o) ? sm[t - o] : 0;
        __syncthreads();
        sm[t] += x;
        __syncthreads();
    }
    if (t < nb) { offA[t + 1] = sm[t]; gcurA[t] = sm[t] - v; }
    if (t == 0) { offA[0] = 0; row_off[N] = E; }
    __syncthreads();
    int vb = (t < nb) ? gcntB[t] : 0;
    sm[t] = vb;
    __syncthreads();
    for (int o = 1; o < 512; o <<= 1) {
        int x = (t >= o) ? sm[t - o] : 0;
        __syncthreads();
        sm[t] += x;
        __syncthreads();
    }
    if (t < nb) { offB[t + 1] = sm[t]; gcurB[t] = sm[t] - vb; }
    if (t == 0) offB[0] = 0;
}

// ---------------- B1: bin edges ----------------
__global__ __launch_bounds__(256) void b1_bin(const int* __restrict__ src,
                                              const int* __restrict__ dst,
                                              int* __restrict__ gcurA,
                                              int* __restrict__ gcurB,
                                              int* __restrict__ binA,
                                              int* __restrict__ binB, int E, int nb) {
    __shared__ int hA[512], hB[512];
    const int t = threadIdx.x;
    for (int b = t; b < nb; b += 256) { hA[b] = 0; hB[b] = 0; }
    __syncthreads();
    const int base = blockIdx.x * EPB;
    int se[16], de[16];
#pragma unroll
    for (int i = 0; i < 16; ++i) {
        int e = base + i * 256 + t;
        se[i] = -1; de[i] = 0;
        if (e < E) {
            se[i] = src[e]; de[i] = dst[e];
            atomicAdd(&hA[de[i] >> 8], 1);
            atomicAdd(&hB[se[i] >> 8], 1);
        }
    }
    __syncthreads();
    for (int b = t; b < nb; b += 256) {
        int c = hA[b];
        hA[b] = c ? atomicAdd(&gcurA[b], c) : 0;
        c = hB[b];
        hB[b] = c ? atomicAdd(&gcurB[b], c) : 0;
    }
    __syncthreads();
#pragma unroll
    for (int i = 0; i < 16; ++i) {
        if (se[i] >= 0) {
            int pA = atomicAdd(&hA[de[i] >> 8], 1);
            binA[pA] = se[i] | ((de[i] & 255) << 17);
            int pB = atomicAdd(&hB[se[i] >> 8], 1);
            binB[pB] = se[i] & 255;
        }
    }
}

// ---------------- B2: per-bucket finalize ----------------
__global__ __launch_bounds__(256) void b2_final(const int* __restrict__ binA,
                                                const int* __restrict__ binB,
                                                const int* __restrict__ offA,
                                                const int* __restrict__ offB,
                                                int* __restrict__ ssrc,
                                                int* __restrict__ row_off,
                                                float* __restrict__ norm_in,
                                                int* __restrict__ degO, int N) {
    __shared__ int h[256], cur[256];
    const int b = blockIdx.x, t = threadIdx.x;
    const int nA0 = offA[b], cntA = offA[b + 1] - nA0;
    const int nodes = min(256, N - b * 256);

    h[t] = 0;
    __syncthreads();
    for (int k = t; k < cntA; k += 256) atomicAdd(&h[binA[nA0 + k] >> 17], 1);
    __syncthreads();

    int v = h[t];
    cur[t] = v;
    __syncthreads();
    for (int o = 1; o < 256; o <<= 1) {
        int x = (t >= o) ? cur[t - o] : 0;
        __syncthreads();
        cur[t] += x;
        __syncthreads();
    }
    const int rbase = nA0 + (cur[t] - v);
    if (t < nodes) {
        row_off[b * 256 + t] = rbase;
        norm_in[b * 256 + t] = (v > 0) ? rsqrtf((float)v) : 0.0f;
    }
    __syncthreads();
    cur[t] = rbase;
    __syncthreads();

    for (int k = t; k < cntA; k += 256) {
        int val = binA[nA0 + k];
        int pos = atomicAdd(&cur[val >> 17], 1);
        ssrc[pos] = val & 0x1FFFF;
    }

    __syncthreads();
    h[t] = 0;
    __syncthreads();
    const int nB0 = offB[b], cntB = offB[b + 1] - nB0;
    for (int k = t; k < cntB; k += 256) atomicAdd(&h[binB[nB0 + k]], 1);
    __syncthreads();
    if (t < nodes) degO[b * 256 + t] = h[t];
}

// ---------------- prep: W (128xM f32, k-major) -> Wtg (c-major bf16 pairs, CPAD cols) ----------------
template <int M, int CPAD>
__global__ __launch_bounds__(256) void prep_w(const float* __restrict__ W,
                                              unsigned int* __restrict__ Wtg) {
    int idx = blockIdx.x * 256 + threadIdx.x;   // CPAD*64 dwords
    if (idx < CPAD * 64) {
        int c = idx >> 6, kk = idx & 63;
        unsigned int pk = 0;
        if (c < M) {
            unsigned short lo = f2bf(W[(2 * kk) * M + c]);
            unsigned short hi = f2bf(W[(2 * kk + 1) * M + c]);
            pk = (unsigned)lo | ((unsigned)hi << 16);
        }
        Wtg[idx] = pk;
    }
}

// ---------------- MFMA GEMM: Tb = bf16( (norm_out .* X) @ W ) ----------------
// CT col-tiles (CT*16 cols), output row stride OSTRIDE bf16.
// Layouts (m89/m92): A row=l&15, k=(l>>4)*8+j; B col=l&15; D col=l&15, row=(l>>4)*4+reg.
template <int CT, int OSTRIDE>
__global__ __launch_bounds__(256, 4) void gemm_mfma(const float* __restrict__ X,
                                                    const int* __restrict__ degO,
                                                    const unsigned int* __restrict__ Wtg,
                                                    unsigned short* __restrict__ Tb,
                                                    int ntiles, int gridWaves) {
    __shared__ unsigned int Wt[CT * 16 * 68];   // [c][k-pair], 68 dwords/row (64 + 4 pad)
    const int t = threadIdx.x;
    for (int idx = t; idx < CT * 16 * 64; idx += 256) {
        int c = idx >> 6, kk = idx & 63;
        Wt[c * 68 + kk] = Wtg[idx];
    }
    __syncthreads();

    const int lane = t & 63;
    const int w = t >> 6;
    const int l15 = lane & 15;
    const int lh = lane >> 4;    // 0..3
    const unsigned short* Wts = reinterpret_cast<const unsigned short*>(Wt);
    const float4* X4 = reinterpret_cast<const float4*>(X);

    for (int tile = blockIdx.x * 4 + w; tile < ntiles; tile += gridWaves) {
        const int row = tile * 16 + l15;
        const int dv = degO[row];
        const float s = (dv > 0) ? rsqrtf((float)dv) : 0.0f;
        const float4* Xr = X4 + ((size_t)row * 32 + lh * 2);

        f32x4 acc[CT];
#pragma unroll
        for (int ct = 0; ct < CT; ++ct) acc[ct] = f32x4{0.f, 0.f, 0.f, 0.f};

#pragma unroll
        for (int kc = 0; kc < 4; ++kc) {
            float4 a0 = Xr[kc * 8];        // k0 = kc*32 + lh*8
            float4 a1 = Xr[kc * 8 + 1];
            short8 af;
            af[0] = (short)f2bf(a0.x * s); af[1] = (short)f2bf(a0.y * s);
            af[2] = (short)f2bf(a0.z * s); af[3] = (short)f2bf(a0.w * s);
            af[4] = (short)f2bf(a1.x * s); af[5] = (short)f2bf(a1.y * s);
            af[6] = (short)f2bf(a1.z * s); af[7] = (short)f2bf(a1.w * s);
            const int k0 = kc * 32 + lh * 8;
#pragma unroll
            for (int ct = 0; ct < CT; ++ct) {
                short8 bf = *reinterpret_cast<const short8*>(&Wts[(ct * 16 + l15) * 136 + k0]);
                acc[ct] = __builtin_amdgcn_mfma_f32_16x16x32_bf16(af, bf, acc[ct], 0, 0, 0);
            }
        }

        const int rbase = tile * 16 + lh * 4;
#pragma unroll
        for (int ct = 0; ct < CT; ++ct) {
            const int col = ct * 16 + l15;
#pragma unroll
            for (int r = 0; r < 4; ++r)
                Tb[(size_t)(rbase + r) * OSTRIDE + col] = f2bf(acc[ct][r]);
        }
    }
}

// ---------------- aggregation over bf16 T, 128 cols (layers 1-2, proven) ----------------
__global__ __launch_bounds__(256) void agg_bf16(const unsigned short* __restrict__ Tb,
                                                const int* __restrict__ row_off,
                                                const int* __restrict__ ssrc,
                                                const float* __restrict__ norm_in,
                                                const float* __restrict__ bias,
                                                float* __restrict__ out, int n) {
    const int wid = (int)((blockIdx.x * blockDim.x + threadIdx.x) >> 6);
    const int lane = threadIdx.x & 63;
    if (wid >= n) return;
    const uint* T2 = reinterpret_cast<const uint*>(Tb);
    const int e0 = row_off[wid], e1 = row_off[wid + 1];
    float ax = 0.f, ay = 0.f;
    int e = e0;
    for (; e + 4 <= e1; e += 4) {
        int s0 = ssrc[e], s1 = ssrc[e + 1], s2 = ssrc[e + 2], s3 = ssrc[e + 3];
        uint v0 = T2[(size_t)s0 * 64 + lane];
        uint v1 = T2[(size_t)s1 * 64 + lane];
        uint v2 = T2[(size_t)s2 * 64 + lane];
        uint v3 = T2[(size_t)s3 * 64 + lane];
        ax += bf2f((unsigned short)v0) + bf2f((unsigned short)v1)
            + bf2f((unsigned short)v2) + bf2f((unsigned short)v3);
        ay += bf2f((unsigned short)(v0 >> 16)) + bf2f((unsigned short)(v1 >> 16))
            + bf2f((unsigned short)(v2 >> 16)) + bf2f((unsigned short)(v3 >> 16));
    }
    for (; e < e1; ++e) {
        uint v = T2[(size_t)ssrc[e] * 64 + lane];
        ax += bf2f((unsigned short)v);
        ay += bf2f((unsigned short)(v >> 16));
    }
    float ni = norm_in[wid];
    float2 b = reinterpret_cast<const float2*>(bias)[lane];
    float ox = fmaxf(ax * ni + b.x, 0.f);
    float oy = fmaxf(ay * ni + b.y, 0.f);
    reinterpret_cast<float2*>(out)[(size_t)wid * 64 + lane] = make_float2(ox, oy);
}

// ---------------- layer-3 aggregation: bf16 T3 (rows padded to 64 = 16 uint2), 4 edges/wave ----
// Groups g=lane>>4 (4 edges in parallel); j=lane&15; j<10 load uint2 = cols 4j..4j+3.
// Trip count is wave-uniform; guards wrap loads only; shfl_xor strictly after the loop.
__global__ __launch_bounds__(256) void agg_f3(const unsigned short* __restrict__ T3,
                                              const int* __restrict__ row_off,
                                              const int* __restrict__ ssrc,
                                              const float* __restrict__ norm_in,
                                              const float* __restrict__ bias,
                                              float* __restrict__ out, int n) {
    const int wid = (int)((blockIdx.x * blockDim.x + threadIdx.x) >> 6);
    const int lane = threadIdx.x & 63;
    if (wid >= n) return;                      // wave-uniform exit
    const int g = lane >> 4;                   // edge-group 0..3
    const int j = lane & 15;                   // col-quad index
    const bool act = (j < 10);                 // 10 quads cover 40 cols

    const int e0 = row_off[wid];
    const int cnt = row_off[wid + 1] - e0;
    const float ni = norm_in[wid];
    const int niter = (cnt + 3) >> 2;          // uniform across the wave

    const uint2* T3q = reinterpret_cast<const uint2*>(T3);   // row = 16 uint2 (64 bf16)

    float a0 = 0.f, a1 = 0.f, a2 = 0.f, a3 = 0.f;
    float c0 = 0.f, c1 = 0.f, c2 = 0.f, c3 = 0.f;
    int it = 0;
    for (; it + 2 <= niter; it += 2) {         // 8 edges in flight per step
        const int i0 = it * 4 + g, i1 = i0 + 4;
        if (act && i0 < cnt) {
            int s = ssrc[e0 + i0];
            uint2 q = T3q[(size_t)s * 16 + j];
            a0 += bf2f((unsigned short)q.x);
            a1 += bf2f((unsigned short)(q.x >> 16));
            a2 += bf2f((unsigned short)q.y);
            a3 += bf2f((unsigned short)(q.y >> 16));
        }
        if (act && i1 < cnt) {
            int s = ssrc[e0 + i1];
            uint2 q = T3q[(size_t)s * 16 + j];
            c0 += bf2f((unsigned short)q.x);
            c1 += bf2f((unsigned short)(q.x >> 16));
            c2 += bf2f((unsigned short)q.y);
            c3 += bf2f((unsigned short)(q.y >> 16));
        }
    }
    if (it < niter) {
        const int i0 = it * 4 + g;
        if (act && i0 < cnt) {
            int s = ssrc[e0 + i0];
            uint2 q = T3q[(size_t)s * 16 + j];
            a0 += bf2f((unsigned short)q.x);
            a1 += bf2f((unsigned short)(q.x >> 16));
            a2 += bf2f((unsigned short)q.y);
            a3 += bf2f((unsigned short)(q.y >> 16));
        }
    }
    a0 += c0; a1 += c1; a2 += c2; a3 += c3;

    // cross-group reduce: ALL 64 lanes execute (uniform control flow here)
#pragma unroll
    for (int m = 16; m < 64; m <<= 1) {
        a0 += __shfl_xor(a0, m, 64);
        a1 += __shfl_xor(a1, m, 64);
        a2 += __shfl_xor(a2, m, 64);
        a3 += __shfl_xor(a3, m, 64);
    }

    if (g == 0 && act) {
        float4 bb = reinterpret_cast<const float4*>(bias)[j];
        float4 o;
        o.x = a0 * ni + bb.x;
        o.y = a1 * ni + bb.y;
        o.z = a2 * ni + bb.z;
        o.w = a3 * ni + bb.w;
        reinterpret_cast<float4*>(out)[(size_t)wid * 10 + j] = o;   // 40 f32/row
    }
}

// ---------------- launch ----------------
extern "C" void kernel_launch(void* const* d_in, const int* in_sizes, int n_in,
                              void* d_out, int out_size, void* d_ws, size_t ws_size,
                              hipStream_t stream) {
    const float* feat = (const float*)d_in[0];
    const int* src = (const int*)d_in[1];
    const int* dst = (const int*)d_in[2];
    const float* W0 = (const float*)d_in[3];
    const float* b0 = (const float*)d_in[4];
    const float* W1 = (const float*)d_in[5];
    const float* b1 = (const float*)d_in[6];
    const float* W2 = (const float*)d_in[7];
    const float* b2 = (const float*)d_in[8];
    float* outp = (float*)d_out;

    const int N = in_sizes[0] / KDIM;   // 100000
    const int E = in_sizes[1];          // 1600000
    const int nb = (N + 255) >> 8;
    const int nblkE = (E + EPB - 1) / EPB;

    auto align = [](size_t x) { return (x + 255) & ~(size_t)255; };
    char* p = (char*)d_ws;
    int* degO      = (int*)p;    p += align((size_t)N * 4);
    float* norm_in = (float*)p;  p += align((size_t)N * 4);
    int* row_off   = (int*)p;    p += align((size_t)(N + 1) * 4);
    int* gcntA     = (int*)p;    p += 512 * 4;
    int* gcntB     = (int*)p;    p += 512 * 4;
    int* offA      = (int*)p;    p += align(513 * 4);
    int* offB      = (int*)p;    p += align(513 * 4);
    int* gcurA     = (int*)p;    p += align(512 * 4);
    int* gcurB     = (int*)p;    p += align(512 * 4);
    unsigned int* W0t = (unsigned int*)p;  p += align(8192 * 4);
    unsigned int* W1t = (unsigned int*)p;  p += align(8192 * 4);
    unsigned int* W2t = (unsigned int*)p;  p += align(3072 * 4);
    int* ssrc      = (int*)p;    p += align((size_t)E * 4);
    float* T       = (float*)p;  p += align((size_t)N * KDIM * 4);
    float* H       = (float*)p;  p += align((size_t)N * KDIM * 4);
    unsigned short* Tb = (unsigned short*)T;   // bf16 [N][128] (layers 1-2)
    unsigned short* T3 = (unsigned short*)T;   // bf16 [N][64]  (layer 3; Tb dead by then)
    int* binA      = (int*)T;                  // build-phase alias, dead before first GEMM
    int* binB      = binA + E;
    (void)n_in; (void)out_size; (void)ws_size;

    const int aggBlocks = (int)(((size_t)N * 64 + 255) / 256);
    const int ntiles = N / 16;                      // 6250
    const int gBlocks = (ntiles + 3) / 4;
    const int gridWaves = gBlocks * 4;

    hipMemsetAsync(gcntA, 0, 1024 * 4, stream);

    prep_w<128, 128><<<32, 256, 0, stream>>>(W0, W0t);
    prep_w<128, 128><<<32, 256, 0, stream>>>(W1, W1t);
    prep_w<40, 48><<<12, 256, 0, stream>>>(W2, W2t);

    b0_count<<<nblkE, 256, 0, stream>>>(src, dst, gcntA, gcntB, E, nb);
    b0b_offsets<<<1, 512, 0, stream>>>(gcntA, gcntB, offA, offB, gcurA, gcurB, row_off, nb, N, E);
    b1_bin<<<nblkE, 256, 0, stream>>>(src, dst, gcurA, gcurB, binA, binB, E, nb);
    b2_final<<<nb, 256, 0, stream>>>(binA, binB, offA, offB, ssrc, row_off, norm_in, degO, N);

    // layer 1: feat -> Tb (bf16, MFMA) -> H
    gemm_mfma<8, 128><<<gBlocks, 256, 0, stream>>>(feat, degO, W0t, Tb, ntiles, gridWaves);
    agg_bf16<<<aggBlocks, 256, 0, stream>>>(Tb, row_off, ssrc, norm_in, b0, H, N);

    // layer 2: H -> Tb (bf16, MFMA) -> H
    gemm_mfma<8, 128><<<gBlocks, 256, 0, stream>>>(H, degO, W1t, Tb, ntiles, gridWaves);
    agg_bf16<<<aggBlocks, 256, 0, stream>>>(Tb, row_off, ssrc, norm_in, b1, H, N);

    // layer 3: H -> T3 (bf16 padded rows, MFMA) -> out (40 f32)
    gemm_mfma<3, 64><<<gBlocks, 256, 0, stream>>>(H, degO, W2t, T3, ntiles, gridWaves);
    agg_f3<<<aggBlocks, 256, 0, stream>>>(T3, row_off, ssrc, norm_in, b2, outp, N);
}